// Round 2
// baseline (259.711 us; speedup 1.0000x reference)
//
#include <hip/hip_runtime.h>
#include <hip/hip_bf16.h>

#define BSZ 16
#define CDIM 256
#define NPIX 1024
#define NH 4
#define DHD 64
#define EPSV 1e-6f
#define QSCALE 0.0625f   // 1/sqrt(DIM)
#define INV_SQRT2 0.70710678118654752440f

typedef __attribute__((ext_vector_type(4))) float f32x4;
typedef __attribute__((ext_vector_type(8))) __bf16 bf16x8;
typedef __attribute__((ext_vector_type(4))) __bf16 bf16x4;

// Workspace layout (bytes). Total = 49.5 MB.
#define OFF_WBF   0UL                          // 4 x 65536 bf16 = 512 KB
#define OFF_STATS (512UL*1024)
#define OFF_ANT   (1024UL*1024)                // [b][p][c] bf16, 8 MB
#define OFF_BNT   (OFF_ANT + 8UL*1024*1024)
#define OFF_Q     (OFF_BNT + 8UL*1024*1024)    // [bh][p][d] bf16
#define OFF_K     (OFF_Q   + 8UL*1024*1024)    // [bh][p][d]
#define OFF_V     (OFF_K   + 8UL*1024*1024)    // [bh][d][p]
#define OFF_H     (OFF_V   + 8UL*1024*1024)    // [b][p][c]

// ---------------- weights -> bf16 (Wq pre-scaled by 1/sqrt(DIM)) -------------
__global__ __launch_bounds__(256) void prep_w(const float* __restrict__ Wq, const float* __restrict__ Wk,
                                              const float* __restrict__ Wv, const float* __restrict__ Wp,
                                              __bf16* __restrict__ out){
  int m = blockIdx.y;
  const float* src = (m==0)?Wq:(m==1)?Wk:(m==2)?Wv:Wp;
  float scale = (m==0)?QSCALE:1.0f;
  int idx = (blockIdx.x*256 + threadIdx.x)*4;
  float4 v = *(const float4*)(src + idx);
  bf16x4 o;
  o[0]=(__bf16)(v.x*scale); o[1]=(__bf16)(v.y*scale);
  o[2]=(__bf16)(v.z*scale); o[3]=(__bf16)(v.w*scale);
  *(bf16x4*)(out + m*65536 + idx) = o;
}

// ---------------- groupnorm stats ------------------------------------------
__global__ __launch_bounds__(256) void gn_stats(const float* __restrict__ xa, const float* __restrict__ xb,
                                                float2* __restrict__ stats){
  int bx = blockIdx.x;              // t(2) * b(16) * g(32)
  int t = bx >> 9; int rem = bx & 511; int bb = rem >> 5; int g = rem & 31;
  const float* src = (t ? xb : xa) + ((size_t)(bb*CDIM + g*8))*NPIX;
  float s = 0.f, ss = 0.f;
  for (int i = 0; i < 8; i++){
    float4 v = *(const float4*)(src + (threadIdx.x + 256*i)*4);
    s  += v.x+v.y+v.z+v.w;
    ss += v.x*v.x+v.y*v.y+v.z*v.z+v.w*v.w;
  }
  __shared__ float rs[256], rss[256];
  rs[threadIdx.x]=s; rss[threadIdx.x]=ss; __syncthreads();
  for (int st=128; st>0; st>>=1){
    if (threadIdx.x < st){ rs[threadIdx.x]+=rs[threadIdx.x+st]; rss[threadIdx.x]+=rss[threadIdx.x+st]; }
    __syncthreads();
  }
  if (threadIdx.x==0){
    float mean = rs[0]*(1.0f/8192.0f);
    float var  = rss[0]*(1.0f/8192.0f) - mean*mean;
    stats[(t*16+bb)*32+g] = make_float2(mean, rsqrtf(var + EPSV));
  }
}

// ------------- normalize + transpose to [b][p][c] bf16 -----------------------
__global__ __launch_bounds__(256) void norm_t(const float* __restrict__ xa, const float* __restrict__ xb,
                                              const float* __restrict__ gAw, const float* __restrict__ gAb,
                                              const float* __restrict__ gBw, const float* __restrict__ gBb,
                                              const float2* __restrict__ stats,
                                              __bf16* __restrict__ ant, __bf16* __restrict__ bnt){
  __shared__ __align__(16) __bf16 T[64][72];
  int t = blockIdx.z;
  const float* src = t ? xb : xa;
  const float* gw  = t ? gBw : gAw;
  const float* gb  = t ? gBb : gAb;
  __bf16* dst = t ? bnt : ant;
  int bb = blockIdx.y >> 2, cblk = blockIdx.y & 3;
  int p0 = blockIdx.x*64, c0 = cblk*64;
  int tid = threadIdx.x;
  int r16 = tid>>4, c4 = tid&15;
  for (int pass=0; pass<4; pass++){
    int cl = r16 + 16*pass;
    int c  = c0 + cl;
    float2 ms = stats[(t*16+bb)*32 + (c>>3)];
    float sc  = ms.y * gw[c];
    float off = gb[c] - ms.x*sc;
    float4 v = *(const float4*)(src + ((size_t)(bb*CDIM + c))*NPIX + p0 + c4*4);
    T[c4*4+0][cl] = (__bf16)(v.x*sc+off);
    T[c4*4+1][cl] = (__bf16)(v.y*sc+off);
    T[c4*4+2][cl] = (__bf16)(v.z*sc+off);
    T[c4*4+3][cl] = (__bf16)(v.w*sc+off);
  }
  __syncthreads();
  for (int pass=0; pass<2; pass++){
    int slot = tid + 256*pass;
    int pl = slot>>3, ch = slot&7;
    *(float4*)(dst + ((size_t)(bb*NPIX + p0 + pl))*CDIM + c0 + ch*8) = *(float4*)&T[pl][ch*8];
  }
}

// ------------- Q+K merged GEMM: 128x128 tile, BK=64, K=256 unrolled ----------
// A = stacked [Wq*s; Wk] (512x256), B = bnt (rows 0-255) / ant (rows 256-511)
__global__ __launch_bounds__(256) void gemm_qk(const __bf16* __restrict__ Wqk,
    const __bf16* __restrict__ bnt, const __bf16* __restrict__ ant,
    const float* __restrict__ bq, const float* __restrict__ bk,
    __bf16* __restrict__ qws, __bf16* __restrict__ kws){
  __shared__ __align__(16) __bf16 As[128][76], Bs[128][76];
  int i0 = blockIdx.x;                       // 512 blocks
  int wg = (i0&7)*64 + (i0>>3);              // XCD swizzle (512%8==0, bijective)
  int my = wg&3, nx = wg>>2;                 // blocks sharing B-tile colocate
  int m0 = my*128, n0 = nx*128;
  const __bf16* Bm = (my<2) ? bnt : ant;
  int tid=threadIdx.x, lane=tid&63, wid=tid>>6;
  int wm=(wid>>1)*64, wn=(wid&1)*64, g=lane>>4, c=lane&15;
  f32x4 acc[4][4];
  #pragma unroll
  for (int i=0;i<4;i++)
    #pragma unroll
    for (int j=0;j<4;j++) acc[i][j]=(f32x4){0.f,0.f,0.f,0.f};
  int row[4], ch[4];
  #pragma unroll
  for (int i=0;i<4;i++){ int slot=tid+256*i; row[i]=slot>>3; ch[i]=slot&7; }
  float4 rA[4], rB[4];
  #pragma unroll
  for (int i=0;i<4;i++){
    rA[i] = *(const float4*)(Wqk + (size_t)(m0+row[i])*256 + ch[i]*8);
    rB[i] = *(const float4*)(Bm  + (size_t)(n0+row[i])*256 + ch[i]*8);
  }
  #pragma unroll
  for (int t=0;t<4;t++){
    #pragma unroll
    for (int i=0;i<4;i++){
      *(float4*)&As[row[i]][ch[i]*8] = rA[i];
      *(float4*)&Bs[row[i]][ch[i]*8] = rB[i];
    }
    __syncthreads();
    if (t<3){
      int k0=(t+1)*64;
      #pragma unroll
      for (int i=0;i<4;i++){
        rA[i] = *(const float4*)(Wqk + (size_t)(m0+row[i])*256 + k0 + ch[i]*8);
        rB[i] = *(const float4*)(Bm  + (size_t)(n0+row[i])*256 + k0 + ch[i]*8);
      }
    }
    #pragma unroll
    for (int ks=0;ks<2;ks++){
      bf16x8 af[4], bfr[4];
      #pragma unroll
      for (int i=0;i<4;i++) af[i]  = *(bf16x8*)&As[wm+i*16+c][ks*32+g*8];
      #pragma unroll
      for (int j=0;j<4;j++) bfr[j] = *(bf16x8*)&Bs[wn+j*16+c][ks*32+g*8];
      #pragma unroll
      for (int i=0;i<4;i++)
        #pragma unroll
        for (int j=0;j<4;j++)
          acc[i][j] = __builtin_amdgcn_mfma_f32_16x16x32_bf16(af[i], bfr[j], acc[i][j],0,0,0);
    }
    __syncthreads();
  }
  const float* bias = (my<2)? bq : bk;
  float bscale = (my<2)? QSCALE : 1.0f;
  __bf16* dst = (my<2)? qws : kws;
  int mbase = (my<2)? m0 : (m0-256);
  #pragma unroll
  for (int fm=0;fm<4;fm++){
    #pragma unroll
    for (int fn=0;fn<4;fn++){
      int o = mbase + wm + fm*16 + g*4;     // out-channel (4 consecutive d)
      int n = n0 + wn + fn*16 + c;
      int bb=n>>10, p=n&1023;
      f32x4 v = acc[fm][fn];
      bf16x4 pk;
      #pragma unroll
      for (int r=0;r<4;r++) pk[r] = (__bf16)(v[r] + bias[o+r]*bscale);
      *(bf16x4*)(dst + ((size_t)((bb*4+(o>>6))*1024 + p))*64 + (o&63)) = pk;
    }
  }
}

// ------------- swapped-orientation GEMM: 128(m=bp) x 64(n=o), K=256 ----------
// mode 0: V   -> bf16 [bh][d][p]
// mode 1: OUT -> fp32 [b][o][p], (skip+acc+bias)*inv_sqrt2
__global__ __launch_bounds__(256) void gemm_sw(const __bf16* __restrict__ A,
    const __bf16* __restrict__ Wn, const float* __restrict__ bias,
    void* __restrict__ dst_, const float* __restrict__ skip, int mode){
  __shared__ __align__(16) __bf16 As[128][76], Bs[64][76];
  int i0 = blockIdx.x;                       // 512 blocks
  int wg = (i0&7)*64 + (i0>>3);
  int ny = wg&3, mx = wg>>2;                 // blocks sharing A-tile colocate
  int m0 = mx*128, n0 = ny*64;
  int tid=threadIdx.x, lane=tid&63, wid=tid>>6;
  int wm=(wid>>1)*64, wn=(wid&1)*32, g=lane>>4, c=lane&15;
  f32x4 acc[4][2];
  #pragma unroll
  for (int i=0;i<4;i++)
    #pragma unroll
    for (int j=0;j<2;j++) acc[i][j]=(f32x4){0.f,0.f,0.f,0.f};
  int rowA[4], chA[4], rowB[2], chB[2];
  #pragma unroll
  for (int i=0;i<4;i++){ int slot=tid+256*i; rowA[i]=slot>>3; chA[i]=slot&7; }
  #pragma unroll
  for (int i=0;i<2;i++){ int slot=tid+256*i; rowB[i]=slot>>3; chB[i]=slot&7; }
  float4 rA[4], rB[2];
  #pragma unroll
  for (int i=0;i<4;i++) rA[i] = *(const float4*)(A  + (size_t)(m0+rowA[i])*256 + chA[i]*8);
  #pragma unroll
  for (int i=0;i<2;i++) rB[i] = *(const float4*)(Wn + (size_t)(n0+rowB[i])*256 + chB[i]*8);
  #pragma unroll
  for (int t=0;t<4;t++){
    #pragma unroll
    for (int i=0;i<4;i++) *(float4*)&As[rowA[i]][chA[i]*8] = rA[i];
    #pragma unroll
    for (int i=0;i<2;i++) *(float4*)&Bs[rowB[i]][chB[i]*8] = rB[i];
    __syncthreads();
    if (t<3){
      int k0=(t+1)*64;
      #pragma unroll
      for (int i=0;i<4;i++) rA[i] = *(const float4*)(A  + (size_t)(m0+rowA[i])*256 + k0 + chA[i]*8);
      #pragma unroll
      for (int i=0;i<2;i++) rB[i] = *(const float4*)(Wn + (size_t)(n0+rowB[i])*256 + k0 + chB[i]*8);
    }
    #pragma unroll
    for (int ks=0;ks<2;ks++){
      bf16x8 af[4], bfr[2];
      #pragma unroll
      for (int i=0;i<4;i++) af[i]  = *(bf16x8*)&As[wm+i*16+c][ks*32+g*8];
      #pragma unroll
      for (int j=0;j<2;j++) bfr[j] = *(bf16x8*)&Bs[wn+j*16+c][ks*32+g*8];
      #pragma unroll
      for (int i=0;i<4;i++)
        #pragma unroll
        for (int j=0;j<2;j++)
          acc[i][j] = __builtin_amdgcn_mfma_f32_16x16x32_bf16(af[i], bfr[j], acc[i][j],0,0,0);
    }
    __syncthreads();
  }
  #pragma unroll
  for (int fm=0;fm<4;fm++){
    #pragma unroll
    for (int fn=0;fn<2;fn++){
      int m = m0 + wm + fm*16 + g*4;        // bp (4 consecutive p)
      int n = n0 + wn + fn*16 + c;          // out-channel
      int bb=m>>10, p=m&1023;
      f32x4 v = acc[fm][fn];
      if (mode==0){
        float bv = bias[n];
        bf16x4 pk;
        #pragma unroll
        for (int r=0;r<4;r++) pk[r] = (__bf16)(v[r] + bv);
        *(bf16x4*)((__bf16*)dst_ + ((size_t)((bb*4+(n>>6))*64 + (n&63)))*1024 + p) = pk;
      } else {
        float bv = bias[n];
        size_t addr = (size_t)(bb*256 + n)*1024 + p;
        float4 sk = *(const float4*)(skip + addr);
        float4 ov;
        ov.x=(sk.x+v[0]+bv)*INV_SQRT2; ov.y=(sk.y+v[1]+bv)*INV_SQRT2;
        ov.z=(sk.z+v[2]+bv)*INV_SQRT2; ov.w=(sk.w+v[3]+bv)*INV_SQRT2;
        *(float4*)((float*)dst_ + addr) = ov;
      }
    }
  }
}

// ------------- attention: per (b,h), 64-query block, T14 prefetch ------------
__global__ __launch_bounds__(256) void attn_k(const __bf16* __restrict__ q, const __bf16* __restrict__ k,
                                              const __bf16* __restrict__ v, __bf16* __restrict__ hout){
  __shared__ __align__(16) __bf16 Kl[64][76], Vl[64][76], Pl[4][16][76];
  __shared__ float l_lds[4][16];
  int i0 = blockIdx.x;                      // 1024 blocks
  int wg = (i0&7)*128 + (i0>>3);            // XCD swizzle: 8 bh-groups per XCD
  int bh = wg>>4, qblk = wg&15;
  int tid = threadIdx.x, lane = tid&63, w = tid>>6;
  int g = lane>>4, c = lane&15;
  int bb = bh>>2, h = bh&3;
  const __bf16* qbase = q + (size_t)bh*NPIX*DHD;
  const __bf16* kbase = k + (size_t)bh*NPIX*DHD;
  const __bf16* vbase = v + (size_t)bh*DHD*NPIX;

  int qrow = qblk*64 + w*16 + c;
  bf16x8 qf0 = *(const bf16x8*)(qbase + (size_t)qrow*64 +      g*8);
  bf16x8 qf1 = *(const bf16x8*)(qbase + (size_t)qrow*64 + 32 + g*8);

  f32x4 oacc[4];
  #pragma unroll
  for (int i=0;i<4;i++) oacc[i] = (f32x4){0.f,0.f,0.f,0.f};
  float l0=0.f, l1=0.f, l2=0.f, l3=0.f;

  int srow[2], sch[2];
  #pragma unroll
  for (int i=0;i<2;i++){ int slot=tid+256*i; srow[i]=slot>>3; sch[i]=slot&7; }
  float4 rK[2], rV[2];
  #pragma unroll
  for (int i=0;i<2;i++){
    rK[i] = *(const float4*)(kbase + (size_t)srow[i]*64 + sch[i]*8);
    rV[i] = *(const float4*)(vbase + (size_t)srow[i]*1024 + sch[i]*8);
  }

  for (int kt=0; kt<16; kt++){
    #pragma unroll
    for (int i=0;i<2;i++){
      *(float4*)&Kl[srow[i]][sch[i]*8] = rK[i];
      *(float4*)&Vl[srow[i]][sch[i]*8] = rV[i];
    }
    __syncthreads();
    if (kt<15){                              // T14: issue next tile before compute
      #pragma unroll
      for (int i=0;i<2;i++){
        rK[i] = *(const float4*)(kbase + (size_t)((kt+1)*64+srow[i])*64 + sch[i]*8);
        rV[i] = *(const float4*)(vbase + (size_t)srow[i]*1024 + (kt+1)*64 + sch[i]*8);
      }
    }
    f32x4 s[4];
    __builtin_amdgcn_s_setprio(1);
    #pragma unroll
    for (int fn=0; fn<4; fn++){
      bf16x8 kb0 = *(bf16x8*)&Kl[fn*16 + c][     g*8];
      bf16x8 kb1 = *(bf16x8*)&Kl[fn*16 + c][32 + g*8];
      f32x4 z = (f32x4){0.f,0.f,0.f,0.f};
      z     = __builtin_amdgcn_mfma_f32_16x16x32_bf16(qf0, kb0, z, 0,0,0);
      s[fn] = __builtin_amdgcn_mfma_f32_16x16x32_bf16(qf1, kb1, z, 0,0,0);
    }
    __builtin_amdgcn_s_setprio(0);
    #pragma unroll
    for (int fn=0; fn<4; fn++){
      float p0 = __expf(s[fn][0]); l0 += p0; Pl[w][g*4+0][fn*16+c] = (__bf16)p0;
      float p1 = __expf(s[fn][1]); l1 += p1; Pl[w][g*4+1][fn*16+c] = (__bf16)p1;
      float p2 = __expf(s[fn][2]); l2 += p2; Pl[w][g*4+2][fn*16+c] = (__bf16)p2;
      float p3 = __expf(s[fn][3]); l3 += p3; Pl[w][g*4+3][fn*16+c] = (__bf16)p3;
    }
    bf16x8 pb0 = *(bf16x8*)&Pl[w][c][     g*8];
    bf16x8 pb1 = *(bf16x8*)&Pl[w][c][32 + g*8];
    __builtin_amdgcn_s_setprio(1);
    #pragma unroll
    for (int fm=0; fm<4; fm++){
      bf16x8 va0 = *(bf16x8*)&Vl[fm*16+c][     g*8];
      bf16x8 va1 = *(bf16x8*)&Vl[fm*16+c][32 + g*8];
      oacc[fm] = __builtin_amdgcn_mfma_f32_16x16x32_bf16(va0, pb0, oacc[fm], 0,0,0);
      oacc[fm] = __builtin_amdgcn_mfma_f32_16x16x32_bf16(va1, pb1, oacc[fm], 0,0,0);
    }
    __builtin_amdgcn_s_setprio(0);
    __syncthreads();
  }

  l0 += __shfl_xor(l0,1); l0 += __shfl_xor(l0,2); l0 += __shfl_xor(l0,4); l0 += __shfl_xor(l0,8);
  l1 += __shfl_xor(l1,1); l1 += __shfl_xor(l1,2); l1 += __shfl_xor(l1,4); l1 += __shfl_xor(l1,8);
  l2 += __shfl_xor(l2,1); l2 += __shfl_xor(l2,2); l2 += __shfl_xor(l2,4); l2 += __shfl_xor(l2,8);
  l3 += __shfl_xor(l3,1); l3 += __shfl_xor(l3,2); l3 += __shfl_xor(l3,4); l3 += __shfl_xor(l3,8);
  float lv = (c==0)?l0:(c==1)?l1:(c==2)?l2:l3;
  if (c < 4) l_lds[w][g*4+c] = lv;
  __syncthreads();
  float linv = 1.0f / l_lds[w][c];

  int qg = qblk*64 + w*16 + c;
  #pragma unroll
  for (int fm=0; fm<4; fm++){
    bf16x4 pk;
    #pragma unroll
    for (int r=0;r<4;r++) pk[r] = (__bf16)(oacc[fm][r]*linv);
    *(bf16x4*)(hout + ((size_t)(bb*NPIX + qg))*CDIM + h*64 + fm*16 + g*4) = pk;
  }
}

extern "C" void kernel_launch(void* const* d_in, const int* in_sizes, int n_in,
                              void* d_out, int out_size, void* d_ws, size_t ws_size,
                              hipStream_t stream) {
  const float* xa  = (const float*)d_in[0];
  const float* xb  = (const float*)d_in[1];
  const float* Wq  = (const float*)d_in[2];
  const float* bq  = (const float*)d_in[3];
  const float* Wk  = (const float*)d_in[4];
  const float* bk  = (const float*)d_in[5];
  const float* Wv  = (const float*)d_in[6];
  const float* bv  = (const float*)d_in[7];
  const float* Wp  = (const float*)d_in[8];
  const float* bp  = (const float*)d_in[9];
  const float* gAw = (const float*)d_in[10];
  const float* gAb = (const float*)d_in[11];
  const float* gBw = (const float*)d_in[12];
  const float* gBb = (const float*)d_in[13];

  char* ws = (char*)d_ws;
  __bf16* wbf   = (__bf16*)(ws + OFF_WBF);
  float2* stats = (float2*)(ws + OFF_STATS);
  __bf16* ant   = (__bf16*)(ws + OFF_ANT);
  __bf16* bnt   = (__bf16*)(ws + OFF_BNT);
  __bf16* qws   = (__bf16*)(ws + OFF_Q);
  __bf16* kws   = (__bf16*)(ws + OFF_K);
  __bf16* vws   = (__bf16*)(ws + OFF_V);
  __bf16* hws   = (__bf16*)(ws + OFF_H);

  prep_w<<<dim3(64,4), 256, 0, stream>>>(Wq, Wk, Wv, Wp, wbf);
  gn_stats<<<1024, 256, 0, stream>>>(xa, xb, stats);
  norm_t<<<dim3(16,64,2), 256, 0, stream>>>(xa, xb, gAw, gAb, gBw, gBb, stats, ant, bnt);
  gemm_qk<<<512, 256, 0, stream>>>(wbf, bnt, ant, bq, bk, qws, kws);
  gemm_sw<<<512, 256, 0, stream>>>(ant, wbf + 2*65536, bv, vws, nullptr, 0);
  attn_k<<<1024, 256, 0, stream>>>(qws, kws, vws, hws);
  gemm_sw<<<512, 256, 0, stream>>>(hws, wbf + 3*65536, bp, d_out, xb, 1);
}

// Round 4
// 256.891 us; speedup vs baseline: 1.0110x; 1.0110x over previous
//
#include <hip/hip_runtime.h>
#include <hip/hip_bf16.h>

#define BSZ 16
#define CDIM 256
#define NPIX 1024
#define NH 4
#define DHD 64
#define EPSV 1e-6f
#define QSCALE 0.0625f   // 1/sqrt(DIM)
#define INV_SQRT2 0.70710678118654752440f

typedef __attribute__((ext_vector_type(4))) float f32x4;
typedef __attribute__((ext_vector_type(8))) __bf16 bf16x8;
typedef __attribute__((ext_vector_type(4))) __bf16 bf16x4;

// Workspace layout (bytes). Total = 49.5 MB.
#define OFF_WBF   0UL                          // 4 x 65536 bf16 = 512 KB
#define OFF_STATS (512UL*1024)
#define OFF_ANT   (1024UL*1024)                // [b][p][c] bf16, 8 MB
#define OFF_BNT   (OFF_ANT + 8UL*1024*1024)
#define OFF_Q     (OFF_BNT + 8UL*1024*1024)    // [bh][p][d] bf16
#define OFF_K     (OFF_Q   + 8UL*1024*1024)    // [bh][p][d]
#define OFF_V     (OFF_K   + 8UL*1024*1024)    // [bh][d][p]
#define OFF_H     (OFF_V   + 8UL*1024*1024)    // [b][p][c]

// ---------------- weights -> bf16 (Wq pre-scaled by 1/sqrt(DIM)) -------------
__global__ __launch_bounds__(256) void prep_w(const float* __restrict__ Wq, const float* __restrict__ Wk,
                                              const float* __restrict__ Wv, const float* __restrict__ Wp,
                                              __bf16* __restrict__ out){
  int m = blockIdx.y;
  const float* src = (m==0)?Wq:(m==1)?Wk:(m==2)?Wv:Wp;
  float scale = (m==0)?QSCALE:1.0f;
  int idx = (blockIdx.x*256 + threadIdx.x)*4;
  float4 v = *(const float4*)(src + idx);
  bf16x4 o;
  o[0]=(__bf16)(v.x*scale); o[1]=(__bf16)(v.y*scale);
  o[2]=(__bf16)(v.z*scale); o[3]=(__bf16)(v.w*scale);
  *(bf16x4*)(out + m*65536 + idx) = o;
}

// ---------------- groupnorm stats ------------------------------------------
__global__ __launch_bounds__(256) void gn_stats(const float* __restrict__ xa, const float* __restrict__ xb,
                                                float2* __restrict__ stats){
  int bx = blockIdx.x;              // t(2) * b(16) * g(32)
  int t = bx >> 9; int rem = bx & 511; int bb = rem >> 5; int g = rem & 31;
  const float* src = (t ? xb : xa) + ((size_t)(bb*CDIM + g*8))*NPIX;
  float s = 0.f, ss = 0.f;
  for (int i = 0; i < 8; i++){
    float4 v = *(const float4*)(src + (threadIdx.x + 256*i)*4);
    s  += v.x+v.y+v.z+v.w;
    ss += v.x*v.x+v.y*v.y+v.z*v.z+v.w*v.w;
  }
  __shared__ float rs[256], rss[256];
  rs[threadIdx.x]=s; rss[threadIdx.x]=ss; __syncthreads();
  for (int st=128; st>0; st>>=1){
    if (threadIdx.x < st){ rs[threadIdx.x]+=rs[threadIdx.x+st]; rss[threadIdx.x]+=rss[threadIdx.x+st]; }
    __syncthreads();
  }
  if (threadIdx.x==0){
    float mean = rs[0]*(1.0f/8192.0f);
    float var  = rss[0]*(1.0f/8192.0f) - mean*mean;
    stats[(t*16+bb)*32+g] = make_float2(mean, rsqrtf(var + EPSV));
  }
}

// ------------- normalize + transpose to [b][p][c] bf16 -----------------------
__global__ __launch_bounds__(256) void norm_t(const float* __restrict__ xa, const float* __restrict__ xb,
                                              const float* __restrict__ gAw, const float* __restrict__ gAb,
                                              const float* __restrict__ gBw, const float* __restrict__ gBb,
                                              const float2* __restrict__ stats,
                                              __bf16* __restrict__ ant, __bf16* __restrict__ bnt){
  __shared__ __align__(16) __bf16 T[64][72];
  int t = blockIdx.z;
  const float* src = t ? xb : xa;
  const float* gw  = t ? gBw : gAw;
  const float* gb  = t ? gBb : gAb;
  __bf16* dst = t ? bnt : ant;
  int bb = blockIdx.y >> 2, cblk = blockIdx.y & 3;
  int p0 = blockIdx.x*64, c0 = cblk*64;
  int tid = threadIdx.x;
  int r16 = tid>>4, c4 = tid&15;
  for (int pass=0; pass<4; pass++){
    int cl = r16 + 16*pass;
    int c  = c0 + cl;
    float2 ms = stats[(t*16+bb)*32 + (c>>3)];
    float sc  = ms.y * gw[c];
    float off = gb[c] - ms.x*sc;
    float4 v = *(const float4*)(src + ((size_t)(bb*CDIM + c))*NPIX + p0 + c4*4);
    T[c4*4+0][cl] = (__bf16)(v.x*sc+off);
    T[c4*4+1][cl] = (__bf16)(v.y*sc+off);
    T[c4*4+2][cl] = (__bf16)(v.z*sc+off);
    T[c4*4+3][cl] = (__bf16)(v.w*sc+off);
  }
  __syncthreads();
  for (int pass=0; pass<2; pass++){
    int slot = tid + 256*pass;
    int pl = slot>>3, ch = slot&7;
    *(float4*)(dst + ((size_t)(bb*NPIX + p0 + pl))*CDIM + c0 + ch*8) = *(float4*)&T[pl][ch*8];
  }
}

// ------------- Q+K merged GEMM: 128x128 tile, BK=64, K=256 unrolled ----------
// A = stacked [Wq*s; Wk] (512x256), B = bnt (rows 0-255) / ant (rows 256-511)
__global__ __launch_bounds__(256,2) void gemm_qk(const __bf16* __restrict__ Wqk,
    const __bf16* __restrict__ bnt, const __bf16* __restrict__ ant,
    const float* __restrict__ bq, const float* __restrict__ bk,
    __bf16* __restrict__ qws, __bf16* __restrict__ kws){
  __shared__ __align__(16) __bf16 As[128][76], Bs[128][76];
  int i0 = blockIdx.x;                       // 512 blocks
  int wg = (i0&7)*64 + (i0>>3);              // XCD swizzle (512%8==0, bijective)
  int my = wg&3, nx = wg>>2;                 // blocks sharing B-tile colocate
  int m0 = my*128, n0 = nx*128;
  const __bf16* Bm = (my<2) ? bnt : ant;
  int tid=threadIdx.x, lane=tid&63, wid=tid>>6;
  int wm=(wid>>1)*64, wn=(wid&1)*64, g=lane>>4, c=lane&15;
  f32x4 acc[4][4];
  #pragma unroll
  for (int i=0;i<4;i++)
    #pragma unroll
    for (int j=0;j<4;j++) acc[i][j]=(f32x4){0.f,0.f,0.f,0.f};
  int row[4], ch[4];
  #pragma unroll
  for (int i=0;i<4;i++){ int slot=tid+256*i; row[i]=slot>>3; ch[i]=slot&7; }
  float4 rA[4], rB[4];
  #pragma unroll
  for (int i=0;i<4;i++){
    rA[i] = *(const float4*)(Wqk + (size_t)(m0+row[i])*256 + ch[i]*8);
    rB[i] = *(const float4*)(Bm  + (size_t)(n0+row[i])*256 + ch[i]*8);
  }
  #pragma unroll
  for (int t=0;t<4;t++){
    #pragma unroll
    for (int i=0;i<4;i++){
      *(float4*)&As[row[i]][ch[i]*8] = rA[i];
      *(float4*)&Bs[row[i]][ch[i]*8] = rB[i];
    }
    __syncthreads();
    if (t<3){
      int k0=(t+1)*64;
      #pragma unroll
      for (int i=0;i<4;i++){
        rA[i] = *(const float4*)(Wqk + (size_t)(m0+row[i])*256 + k0 + ch[i]*8);
        rB[i] = *(const float4*)(Bm  + (size_t)(n0+row[i])*256 + k0 + ch[i]*8);
      }
    }
    #pragma unroll
    for (int ks=0;ks<2;ks++){
      bf16x8 af[4], bfr[4];
      #pragma unroll
      for (int i=0;i<4;i++) af[i]  = *(bf16x8*)&As[wm+i*16+c][ks*32+g*8];
      #pragma unroll
      for (int j=0;j<4;j++) bfr[j] = *(bf16x8*)&Bs[wn+j*16+c][ks*32+g*8];
      #pragma unroll
      for (int i=0;i<4;i++)
        #pragma unroll
        for (int j=0;j<4;j++)
          acc[i][j] = __builtin_amdgcn_mfma_f32_16x16x32_bf16(af[i], bfr[j], acc[i][j],0,0,0);
    }
    __syncthreads();
  }
  const float* bias = (my<2)? bq : bk;
  float bscale = (my<2)? QSCALE : 1.0f;
  __bf16* dst = (my<2)? qws : kws;
  int mbase = (my<2)? m0 : (m0-256);
  #pragma unroll
  for (int fm=0;fm<4;fm++){
    #pragma unroll
    for (int fn=0;fn<4;fn++){
      int o = mbase + wm + fm*16 + g*4;     // out-channel (4 consecutive d)
      int n = n0 + wn + fn*16 + c;
      int bb=n>>10, p=n&1023;
      f32x4 v = acc[fm][fn];
      bf16x4 pk;
      #pragma unroll
      for (int r=0;r<4;r++) pk[r] = (__bf16)(v[r] + bias[o+r]*bscale);
      *(bf16x4*)(dst + ((size_t)((bb*4+(o>>6))*1024 + p))*64 + (o&63)) = pk;
    }
  }
}

// ------------- swapped-orientation GEMM: 128(m=bp) x 64(n=o), K=256 ----------
// mode 0: V   -> bf16 [bh][d][p]
// mode 1: OUT -> fp32 [b][o][p], (skip+acc+bias)*inv_sqrt2
__global__ __launch_bounds__(256,2) void gemm_sw(const __bf16* __restrict__ A,
    const __bf16* __restrict__ Wn, const float* __restrict__ bias,
    void* __restrict__ dst_, const float* __restrict__ skip, int mode){
  __shared__ __align__(16) __bf16 As[128][76], Bs[64][76];
  int i0 = blockIdx.x;                       // 512 blocks
  int wg = (i0&7)*64 + (i0>>3);
  int ny = wg&3, mx = wg>>2;                 // blocks sharing A-tile colocate
  int m0 = mx*128, n0 = ny*64;
  int tid=threadIdx.x, lane=tid&63, wid=tid>>6;
  int wm=(wid>>1)*64, wn=(wid&1)*32, g=lane>>4, c=lane&15;
  f32x4 acc[4][2];
  #pragma unroll
  for (int i=0;i<4;i++)
    #pragma unroll
    for (int j=0;j<2;j++) acc[i][j]=(f32x4){0.f,0.f,0.f,0.f};
  int rowA[4], chA[4], rowB[2], chB[2];
  #pragma unroll
  for (int i=0;i<4;i++){ int slot=tid+256*i; rowA[i]=slot>>3; chA[i]=slot&7; }
  #pragma unroll
  for (int i=0;i<2;i++){ int slot=tid+256*i; rowB[i]=slot>>3; chB[i]=slot&7; }
  float4 rA[4], rB[2];
  #pragma unroll
  for (int i=0;i<4;i++) rA[i] = *(const float4*)(A  + (size_t)(m0+rowA[i])*256 + chA[i]*8);
  #pragma unroll
  for (int i=0;i<2;i++) rB[i] = *(const float4*)(Wn + (size_t)(n0+rowB[i])*256 + chB[i]*8);
  #pragma unroll
  for (int t=0;t<4;t++){
    #pragma unroll
    for (int i=0;i<4;i++) *(float4*)&As[rowA[i]][chA[i]*8] = rA[i];
    #pragma unroll
    for (int i=0;i<2;i++) *(float4*)&Bs[rowB[i]][chB[i]*8] = rB[i];
    __syncthreads();
    if (t<3){
      int k0=(t+1)*64;
      #pragma unroll
      for (int i=0;i<4;i++) rA[i] = *(const float4*)(A  + (size_t)(m0+rowA[i])*256 + k0 + chA[i]*8);
      #pragma unroll
      for (int i=0;i<2;i++) rB[i] = *(const float4*)(Wn + (size_t)(n0+rowB[i])*256 + k0 + chB[i]*8);
    }
    #pragma unroll
    for (int ks=0;ks<2;ks++){
      bf16x8 af[4], bfr[2];
      #pragma unroll
      for (int i=0;i<4;i++) af[i]  = *(bf16x8*)&As[wm+i*16+c][ks*32+g*8];
      #pragma unroll
      for (int j=0;j<2;j++) bfr[j] = *(bf16x8*)&Bs[wn+j*16+c][ks*32+g*8];
      #pragma unroll
      for (int i=0;i<4;i++)
        #pragma unroll
        for (int j=0;j<2;j++)
          acc[i][j] = __builtin_amdgcn_mfma_f32_16x16x32_bf16(af[i], bfr[j], acc[i][j],0,0,0);
    }
    __syncthreads();
  }
  #pragma unroll
  for (int fm=0;fm<4;fm++){
    #pragma unroll
    for (int fn=0;fn<2;fn++){
      int m = m0 + wm + fm*16 + g*4;        // bp (4 consecutive p)
      int n = n0 + wn + fn*16 + c;          // out-channel
      int bb=m>>10, p=m&1023;
      f32x4 v = acc[fm][fn];
      if (mode==0){
        float bv = bias[n];
        bf16x4 pk;
        #pragma unroll
        for (int r=0;r<4;r++) pk[r] = (__bf16)(v[r] + bv);
        *(bf16x4*)((__bf16*)dst_ + ((size_t)((bb*4+(n>>6))*64 + (n&63)))*1024 + p) = pk;
      } else {
        float bv = bias[n];
        size_t addr = (size_t)(bb*256 + n)*1024 + p;
        float4 sk = *(const float4*)(skip + addr);
        float4 ov;
        ov.x=(sk.x+v[0]+bv)*INV_SQRT2; ov.y=(sk.y+v[1]+bv)*INV_SQRT2;
        ov.z=(sk.z+v[2]+bv)*INV_SQRT2; ov.w=(sk.w+v[3]+bv)*INV_SQRT2;
        *(float4*)((float*)dst_ + addr) = ov;
      }
    }
  }
}

// ------------- attention: per (b,h), 64-query block, T14 prefetch ------------
__global__ __launch_bounds__(256,4) void attn_k(const __bf16* __restrict__ q, const __bf16* __restrict__ k,
                                                const __bf16* __restrict__ v, __bf16* __restrict__ hout){
  __shared__ __align__(16) __bf16 Kl[64][76], Vl[64][76], Pl[4][16][76];
  __shared__ float l_lds[4][16];
  int i0 = blockIdx.x;                      // 1024 blocks
  int wg = (i0&7)*128 + (i0>>3);            // XCD swizzle: 8 bh-groups per XCD
  int bh = wg>>4, qblk = wg&15;
  int tid = threadIdx.x, lane = tid&63, w = tid>>6;
  int g = lane>>4, c = lane&15;
  int bb = bh>>2, h = bh&3;
  const __bf16* qbase = q + (size_t)bh*NPIX*DHD;
  const __bf16* kbase = k + (size_t)bh*NPIX*DHD;
  const __bf16* vbase = v + (size_t)bh*DHD*NPIX;

  int qrow = qblk*64 + w*16 + c;
  bf16x8 qf0 = *(const bf16x8*)(qbase + (size_t)qrow*64 +      g*8);
  bf16x8 qf1 = *(const bf16x8*)(qbase + (size_t)qrow*64 + 32 + g*8);

  f32x4 oacc[4];
  #pragma unroll
  for (int i=0;i<4;i++) oacc[i] = (f32x4){0.f,0.f,0.f,0.f};
  float l0=0.f, l1=0.f, l2=0.f, l3=0.f;

  int srow[2], sch[2];
  #pragma unroll
  for (int i=0;i<2;i++){ int slot=tid+256*i; srow[i]=slot>>3; sch[i]=slot&7; }
  float4 rK[2], rV[2];
  #pragma unroll
  for (int i=0;i<2;i++){
    rK[i] = *(const float4*)(kbase + (size_t)srow[i]*64 + sch[i]*8);
    rV[i] = *(const float4*)(vbase + (size_t)srow[i]*1024 + sch[i]*8);
  }

  for (int kt=0; kt<16; kt++){
    #pragma unroll
    for (int i=0;i<2;i++){
      *(float4*)&Kl[srow[i]][sch[i]*8] = rK[i];
      *(float4*)&Vl[srow[i]][sch[i]*8] = rV[i];
    }
    __syncthreads();
    if (kt<15){                              // T14: issue next tile before compute
      #pragma unroll
      for (int i=0;i<2;i++){
        rK[i] = *(const float4*)(kbase + (size_t)((kt+1)*64+srow[i])*64 + sch[i]*8);
        rV[i] = *(const float4*)(vbase + (size_t)srow[i]*1024 + (kt+1)*64 + sch[i]*8);
      }
    }
    f32x4 s[4];
    __builtin_amdgcn_s_setprio(1);
    #pragma unroll
    for (int fn=0; fn<4; fn++){
      bf16x8 kb0 = *(bf16x8*)&Kl[fn*16 + c][     g*8];
      bf16x8 kb1 = *(bf16x8*)&Kl[fn*16 + c][32 + g*8];
      f32x4 z = (f32x4){0.f,0.f,0.f,0.f};
      z     = __builtin_amdgcn_mfma_f32_16x16x32_bf16(qf0, kb0, z, 0,0,0);
      s[fn] = __builtin_amdgcn_mfma_f32_16x16x32_bf16(qf1, kb1, z, 0,0,0);
    }
    __builtin_amdgcn_s_setprio(0);
    #pragma unroll
    for (int fn=0; fn<4; fn++){
      float p0 = __expf(s[fn][0]); l0 += p0; Pl[w][g*4+0][fn*16+c] = (__bf16)p0;
      float p1 = __expf(s[fn][1]); l1 += p1; Pl[w][g*4+1][fn*16+c] = (__bf16)p1;
      float p2 = __expf(s[fn][2]); l2 += p2; Pl[w][g*4+2][fn*16+c] = (__bf16)p2;
      float p3 = __expf(s[fn][3]); l3 += p3; Pl[w][g*4+3][fn*16+c] = (__bf16)p3;
    }
    bf16x8 pb0 = *(bf16x8*)&Pl[w][c][     g*8];
    bf16x8 pb1 = *(bf16x8*)&Pl[w][c][32 + g*8];
    __builtin_amdgcn_s_setprio(1);
    #pragma unroll
    for (int fm=0; fm<4; fm++){
      bf16x8 va0 = *(bf16x8*)&Vl[fm*16+c][     g*8];
      bf16x8 va1 = *(bf16x8*)&Vl[fm*16+c][32 + g*8];
      oacc[fm] = __builtin_amdgcn_mfma_f32_16x16x32_bf16(va0, pb0, oacc[fm], 0,0,0);
      oacc[fm] = __builtin_amdgcn_mfma_f32_16x16x32_bf16(va1, pb1, oacc[fm], 0,0,0);
    }
    __builtin_amdgcn_s_setprio(0);
    __syncthreads();
  }

  l0 += __shfl_xor(l0,1); l0 += __shfl_xor(l0,2); l0 += __shfl_xor(l0,4); l0 += __shfl_xor(l0,8);
  l1 += __shfl_xor(l1,1); l1 += __shfl_xor(l1,2); l1 += __shfl_xor(l1,4); l1 += __shfl_xor(l1,8);
  l2 += __shfl_xor(l2,1); l2 += __shfl_xor(l2,2); l2 += __shfl_xor(l2,4); l2 += __shfl_xor(l2,8);
  l3 += __shfl_xor(l3,1); l3 += __shfl_xor(l3,2); l3 += __shfl_xor(l3,4); l3 += __shfl_xor(l3,8);
  float lv = (c==0)?l0:(c==1)?l1:(c==2)?l2:l3;
  if (c < 4) l_lds[w][g*4+c] = lv;
  __syncthreads();
  float linv = 1.0f / l_lds[w][c];

  int qg = qblk*64 + w*16 + c;
  #pragma unroll
  for (int fm=0; fm<4; fm++){
    bf16x4 pk;
    #pragma unroll
    for (int r=0;r<4;r++) pk[r] = (__bf16)(oacc[fm][r]*linv);
    *(bf16x4*)(hout + ((size_t)(bb*NPIX + qg))*CDIM + h*64 + fm*16 + g*4) = pk;
  }
}

extern "C" void kernel_launch(void* const* d_in, const int* in_sizes, int n_in,
                              void* d_out, int out_size, void* d_ws, size_t ws_size,
                              hipStream_t stream) {
  const float* xa  = (const float*)d_in[0];
  const float* xb  = (const float*)d_in[1];
  const float* Wq  = (const float*)d_in[2];
  const float* bq  = (const float*)d_in[3];
  const float* Wk  = (const float*)d_in[4];
  const float* bk  = (const float*)d_in[5];
  const float* Wv  = (const float*)d_in[6];
  const float* bv  = (const float*)d_in[7];
  const float* Wp  = (const float*)d_in[8];
  const float* bp  = (const float*)d_in[9];
  const float* gAw = (const float*)d_in[10];
  const float* gAb = (const float*)d_in[11];
  const float* gBw = (const float*)d_in[12];
  const float* gBb = (const float*)d_in[13];

  char* ws = (char*)d_ws;
  __bf16* wbf   = (__bf16*)(ws + OFF_WBF);
  float2* stats = (float2*)(ws + OFF_STATS);
  __bf16* ant   = (__bf16*)(ws + OFF_ANT);
  __bf16* bnt   = (__bf16*)(ws + OFF_BNT);
  __bf16* qws   = (__bf16*)(ws + OFF_Q);
  __bf16* kws   = (__bf16*)(ws + OFF_K);
  __bf16* vws   = (__bf16*)(ws + OFF_V);
  __bf16* hws   = (__bf16*)(ws + OFF_H);

  prep_w<<<dim3(64,4), 256, 0, stream>>>(Wq, Wk, Wv, Wp, wbf);
  gn_stats<<<1024, 256, 0, stream>>>(xa, xb, stats);
  norm_t<<<dim3(16,64,2), 256, 0, stream>>>(xa, xb, gAw, gAb, gBw, gBb, stats, ant, bnt);
  gemm_qk<<<512, 256, 0, stream>>>(wbf, bnt, ant, bq, bk, qws, kws);
  gemm_sw<<<512, 256, 0, stream>>>(ant, wbf + 2*65536, bv, vws, nullptr, 0);
  attn_k<<<1024, 256, 0, stream>>>(qws, kws, vws, hws);
  gemm_sw<<<512, 256, 0, stream>>>(hws, wbf + 3*65536, bp, d_out, xb, 1);
}

// Round 5
// 182.296 us; speedup vs baseline: 1.4247x; 1.4092x over previous
//
#include <hip/hip_runtime.h>
#include <hip/hip_bf16.h>

#define BSZ 16
#define CDIM 256
#define NPIX 1024
#define NH 4
#define DHD 64
#define EPSV 1e-6f
#define QSCALE 0.0625f   // 1/sqrt(DIM)
#define INV_SQRT2 0.70710678118654752440f

typedef __attribute__((ext_vector_type(4))) float f32x4;
typedef __attribute__((ext_vector_type(8))) __bf16 bf16x8;
typedef __attribute__((ext_vector_type(4))) __bf16 bf16x4;

// Workspace layout (bytes). Total = 49.5 MB.
#define OFF_WBF   0UL                          // 4 x 65536 bf16 = 512 KB
#define OFF_STATS (512UL*1024)
#define OFF_ANT   (1024UL*1024)                // [b][p][c] bf16, 8 MB
#define OFF_BNT   (OFF_ANT + 8UL*1024*1024)
#define OFF_Q     (OFF_BNT + 8UL*1024*1024)    // [bh][p][d] bf16
#define OFF_K     (OFF_Q   + 8UL*1024*1024)    // [bh][p][d]
#define OFF_V     (OFF_K   + 8UL*1024*1024)    // [bh][d][p]
#define OFF_H     (OFF_V   + 8UL*1024*1024)    // [b][p][c]

// ---------------- weights -> bf16 (Wq pre-scaled by 1/sqrt(DIM)) -------------
__global__ __launch_bounds__(256) void prep_w(const float* __restrict__ Wq, const float* __restrict__ Wk,
                                              const float* __restrict__ Wv, const float* __restrict__ Wp,
                                              __bf16* __restrict__ out){
  int m = blockIdx.y;
  const float* src = (m==0)?Wq:(m==1)?Wk:(m==2)?Wv:Wp;
  float scale = (m==0)?QSCALE:1.0f;
  int idx = (blockIdx.x*256 + threadIdx.x)*4;
  float4 v = *(const float4*)(src + idx);
  bf16x4 o;
  o[0]=(__bf16)(v.x*scale); o[1]=(__bf16)(v.y*scale);
  o[2]=(__bf16)(v.z*scale); o[3]=(__bf16)(v.w*scale);
  *(bf16x4*)(out + m*65536 + idx) = o;
}

// ---------------- groupnorm stats ------------------------------------------
__global__ __launch_bounds__(256) void gn_stats(const float* __restrict__ xa, const float* __restrict__ xb,
                                                float2* __restrict__ stats){
  int bx = blockIdx.x;              // t(2) * b(16) * g(32)
  int t = bx >> 9; int rem = bx & 511; int bb = rem >> 5; int g = rem & 31;
  const float* src = (t ? xb : xa) + ((size_t)(bb*CDIM + g*8))*NPIX;
  float s = 0.f, ss = 0.f;
  for (int i = 0; i < 8; i++){
    float4 v = *(const float4*)(src + (threadIdx.x + 256*i)*4);
    s  += v.x+v.y+v.z+v.w;
    ss += v.x*v.x+v.y*v.y+v.z*v.z+v.w*v.w;
  }
  __shared__ float rs[256], rss[256];
  rs[threadIdx.x]=s; rss[threadIdx.x]=ss; __syncthreads();
  for (int st=128; st>0; st>>=1){
    if (threadIdx.x < st){ rs[threadIdx.x]+=rs[threadIdx.x+st]; rss[threadIdx.x]+=rss[threadIdx.x+st]; }
    __syncthreads();
  }
  if (threadIdx.x==0){
    float mean = rs[0]*(1.0f/8192.0f);
    float var  = rss[0]*(1.0f/8192.0f) - mean*mean;
    stats[(t*16+bb)*32+g] = make_float2(mean, rsqrtf(var + EPSV));
  }
}

// ------------- normalize + transpose to [b][p][c] bf16 -----------------------
__global__ __launch_bounds__(256) void norm_t(const float* __restrict__ xa, const float* __restrict__ xb,
                                              const float* __restrict__ gAw, const float* __restrict__ gAb,
                                              const float* __restrict__ gBw, const float* __restrict__ gBb,
                                              const float2* __restrict__ stats,
                                              __bf16* __restrict__ ant, __bf16* __restrict__ bnt){
  __shared__ __align__(16) __bf16 T[64][72];
  int t = blockIdx.z;
  const float* src = t ? xb : xa;
  const float* gw  = t ? gBw : gAw;
  const float* gb  = t ? gBb : gAb;
  __bf16* dst = t ? bnt : ant;
  int bb = blockIdx.y >> 2, cblk = blockIdx.y & 3;
  int p0 = blockIdx.x*64, c0 = cblk*64;
  int tid = threadIdx.x;
  int r16 = tid>>4, c4 = tid&15;
  for (int pass=0; pass<4; pass++){
    int cl = r16 + 16*pass;
    int c  = c0 + cl;
    float2 ms = stats[(t*16+bb)*32 + (c>>3)];
    float sc  = ms.y * gw[c];
    float off = gb[c] - ms.x*sc;
    float4 v = *(const float4*)(src + ((size_t)(bb*CDIM + c))*NPIX + p0 + c4*4);
    T[c4*4+0][cl] = (__bf16)(v.x*sc+off);
    T[c4*4+1][cl] = (__bf16)(v.y*sc+off);
    T[c4*4+2][cl] = (__bf16)(v.z*sc+off);
    T[c4*4+3][cl] = (__bf16)(v.w*sc+off);
  }
  __syncthreads();
  for (int pass=0; pass<2; pass++){
    int slot = tid + 256*pass;
    int pl = slot>>3, ch = slot&7;
    *(float4*)(dst + ((size_t)(bb*NPIX + p0 + pl))*CDIM + c0 + ch*8) = *(float4*)&T[pl][ch*8];
  }
}

// ------------- Q+K merged GEMM: 128x128 tile, BK=64, direct staging ----------
// A = stacked [Wq*s; Wk] (512x256), B = bnt (rows 0-255) / ant (rows 256-511)
__global__ __launch_bounds__(256,2) void gemm_qk(const __bf16* __restrict__ Wqk,
    const __bf16* __restrict__ bnt, const __bf16* __restrict__ ant,
    const float* __restrict__ bq, const float* __restrict__ bk,
    __bf16* __restrict__ qws, __bf16* __restrict__ kws){
  __shared__ __align__(16) __bf16 As[128][76], Bs[128][76];
  int i0 = blockIdx.x;                       // 512 blocks
  int wg = (i0&7)*64 + (i0>>3);              // XCD swizzle (512%8==0, bijective)
  int my = wg&3, nx = wg>>2;                 // blocks sharing B-tile colocate
  int m0 = my*128, n0 = nx*128;
  const __bf16* Bm = (my<2) ? bnt : ant;
  int tid=threadIdx.x, lane=tid&63, wid=tid>>6;
  int wm=(wid>>1)*64, wn=(wid&1)*64, g=lane>>4, c=lane&15;
  f32x4 acc[4][4];
  #pragma unroll
  for (int i=0;i<4;i++)
    #pragma unroll
    for (int j=0;j<4;j++) acc[i][j]=(f32x4){0.f,0.f,0.f,0.f};
  int row[4], ch[4];
  #pragma unroll
  for (int i=0;i<4;i++){ int slot=tid+256*i; row[i]=slot>>3; ch[i]=slot&7; }
  for (int k0=0; k0<256; k0+=64){
    #pragma unroll
    for (int i=0;i<4;i++){
      *(float4*)&As[row[i]][ch[i]*8] = *(const float4*)(Wqk + (size_t)(m0+row[i])*256 + k0 + ch[i]*8);
      *(float4*)&Bs[row[i]][ch[i]*8] = *(const float4*)(Bm  + (size_t)(n0+row[i])*256 + k0 + ch[i]*8);
    }
    __syncthreads();
    #pragma unroll
    for (int ks=0;ks<2;ks++){
      bf16x8 af[4], bfr[4];
      #pragma unroll
      for (int i=0;i<4;i++) af[i]  = *(bf16x8*)&As[wm+i*16+c][ks*32+g*8];
      #pragma unroll
      for (int j=0;j<4;j++) bfr[j] = *(bf16x8*)&Bs[wn+j*16+c][ks*32+g*8];
      #pragma unroll
      for (int i=0;i<4;i++)
        #pragma unroll
        for (int j=0;j<4;j++)
          acc[i][j] = __builtin_amdgcn_mfma_f32_16x16x32_bf16(af[i], bfr[j], acc[i][j],0,0,0);
    }
    __syncthreads();
  }
  const float* bias = (my<2)? bq : bk;
  float bscale = (my<2)? QSCALE : 1.0f;
  __bf16* dst = (my<2)? qws : kws;
  int mbase = (my<2)? m0 : (m0-256);
  #pragma unroll
  for (int fm=0;fm<4;fm++){
    #pragma unroll
    for (int fn=0;fn<4;fn++){
      int o = mbase + wm + fm*16 + g*4;     // out-channel (4 consecutive d)
      int n = n0 + wn + fn*16 + c;
      int bb=n>>10, p=n&1023;
      f32x4 v = acc[fm][fn];
      bf16x4 pk;
      #pragma unroll
      for (int r=0;r<4;r++) pk[r] = (__bf16)(v[r] + bias[o+r]*bscale);
      *(bf16x4*)(dst + ((size_t)((bb*4+(o>>6))*1024 + p))*64 + (o&63)) = pk;
    }
  }
}

// ------------- swapped-orientation GEMM: 128(m=bp) x 64(n=o), direct staging -
// mode 0: V   -> bf16 [bh][d][p]
// mode 1: OUT -> fp32 [b][o][p], (skip+acc+bias)*inv_sqrt2
__global__ __launch_bounds__(256,2) void gemm_sw(const __bf16* __restrict__ A,
    const __bf16* __restrict__ Wn, const float* __restrict__ bias,
    void* __restrict__ dst_, const float* __restrict__ skip, int mode){
  __shared__ __align__(16) __bf16 As[128][76], Bs[64][76];
  int i0 = blockIdx.x;                       // 512 blocks
  int wg = (i0&7)*64 + (i0>>3);
  int ny = wg&3, mx = wg>>2;                 // blocks sharing A-tile colocate
  int m0 = mx*128, n0 = ny*64;
  int tid=threadIdx.x, lane=tid&63, wid=tid>>6;
  int wm=(wid>>1)*64, wn=(wid&1)*32, g=lane>>4, c=lane&15;
  f32x4 acc[4][2];
  #pragma unroll
  for (int i=0;i<4;i++)
    #pragma unroll
    for (int j=0;j<2;j++) acc[i][j]=(f32x4){0.f,0.f,0.f,0.f};
  int rowA[4], chA[4], rowB[2], chB[2];
  #pragma unroll
  for (int i=0;i<4;i++){ int slot=tid+256*i; rowA[i]=slot>>3; chA[i]=slot&7; }
  #pragma unroll
  for (int i=0;i<2;i++){ int slot=tid+256*i; rowB[i]=slot>>3; chB[i]=slot&7; }
  for (int k0=0; k0<256; k0+=64){
    #pragma unroll
    for (int i=0;i<4;i++)
      *(float4*)&As[rowA[i]][chA[i]*8] = *(const float4*)(A  + (size_t)(m0+rowA[i])*256 + k0 + chA[i]*8);
    #pragma unroll
    for (int i=0;i<2;i++)
      *(float4*)&Bs[rowB[i]][chB[i]*8] = *(const float4*)(Wn + (size_t)(n0+rowB[i])*256 + k0 + chB[i]*8);
    __syncthreads();
    #pragma unroll
    for (int ks=0;ks<2;ks++){
      bf16x8 af[4], bfr[2];
      #pragma unroll
      for (int i=0;i<4;i++) af[i]  = *(bf16x8*)&As[wm+i*16+c][ks*32+g*8];
      #pragma unroll
      for (int j=0;j<2;j++) bfr[j] = *(bf16x8*)&Bs[wn+j*16+c][ks*32+g*8];
      #pragma unroll
      for (int i=0;i<4;i++)
        #pragma unroll
        for (int j=0;j<2;j++)
          acc[i][j] = __builtin_amdgcn_mfma_f32_16x16x32_bf16(af[i], bfr[j], acc[i][j],0,0,0);
    }
    __syncthreads();
  }
  #pragma unroll
  for (int fm=0;fm<4;fm++){
    #pragma unroll
    for (int fn=0;fn<2;fn++){
      int m = m0 + wm + fm*16 + g*4;        // bp (4 consecutive p)
      int n = n0 + wn + fn*16 + c;          // out-channel
      int bb=m>>10, p=m&1023;
      f32x4 v = acc[fm][fn];
      if (mode==0){
        float bv = bias[n];
        bf16x4 pk;
        #pragma unroll
        for (int r=0;r<4;r++) pk[r] = (__bf16)(v[r] + bv);
        *(bf16x4*)((__bf16*)dst_ + ((size_t)((bb*4+(n>>6))*64 + (n&63)))*1024 + p) = pk;
      } else {
        float bv = bias[n];
        size_t addr = (size_t)(bb*256 + n)*1024 + p;
        float4 sk = *(const float4*)(skip + addr);
        float4 ov;
        ov.x=(sk.x+v[0]+bv)*INV_SQRT2; ov.y=(sk.y+v[1]+bv)*INV_SQRT2;
        ov.z=(sk.z+v[2]+bv)*INV_SQRT2; ov.w=(sk.w+v[3]+bv)*INV_SQRT2;
        *(float4*)((float*)dst_ + addr) = ov;
      }
    }
  }
}

// ------------- attention: R1 body + XCD swizzle + pad-76 ---------------------
__global__ __launch_bounds__(256,4) void attn_k(const __bf16* __restrict__ q, const __bf16* __restrict__ k,
                                                const __bf16* __restrict__ v, __bf16* __restrict__ hout){
  __shared__ __align__(16) __bf16 Kl[64][76], Vl[64][76], Pl[4][16][76];
  __shared__ float l_lds[4][16];
  int i0 = blockIdx.x;                      // 1024 blocks
  int wg = (i0&7)*128 + (i0>>3);            // XCD swizzle: 8 bh-groups per XCD
  int bh = wg>>4, qblk = wg&15;
  int tid = threadIdx.x, lane = tid&63, w = tid>>6;
  int g = lane>>4, c = lane&15;
  int bb = bh>>2, h = bh&3;
  const __bf16* qbase = q + (size_t)bh*NPIX*DHD;
  const __bf16* kbase = k + (size_t)bh*NPIX*DHD;
  const __bf16* vbase = v + (size_t)bh*DHD*NPIX;

  int qrow = qblk*64 + w*16 + c;
  bf16x8 qf0 = *(const bf16x8*)(qbase + (size_t)qrow*64 +      g*8);
  bf16x8 qf1 = *(const bf16x8*)(qbase + (size_t)qrow*64 + 32 + g*8);

  f32x4 oacc[4];
  #pragma unroll
  for (int i=0;i<4;i++) oacc[i] = (f32x4){0.f,0.f,0.f,0.f};
  float l0=0.f, l1=0.f, l2=0.f, l3=0.f;

  int srow[2], sch[2];
  #pragma unroll
  for (int i=0;i<2;i++){ int slot=tid+256*i; srow[i]=slot>>3; sch[i]=slot&7; }

  for (int kt=0; kt<16; kt++){
    #pragma unroll
    for (int i=0;i<2;i++){
      *(float4*)&Kl[srow[i]][sch[i]*8] = *(const float4*)(kbase + (size_t)(kt*64+srow[i])*64 + sch[i]*8);
      *(float4*)&Vl[srow[i]][sch[i]*8] = *(const float4*)(vbase + (size_t)srow[i]*1024 + kt*64 + sch[i]*8);
    }
    __syncthreads();
    f32x4 s[4];
    #pragma unroll
    for (int fn=0; fn<4; fn++){
      bf16x8 kb0 = *(bf16x8*)&Kl[fn*16 + c][     g*8];
      bf16x8 kb1 = *(bf16x8*)&Kl[fn*16 + c][32 + g*8];
      f32x4 z = (f32x4){0.f,0.f,0.f,0.f};
      z     = __builtin_amdgcn_mfma_f32_16x16x32_bf16(qf0, kb0, z, 0,0,0);
      s[fn] = __builtin_amdgcn_mfma_f32_16x16x32_bf16(qf1, kb1, z, 0,0,0);
    }
    #pragma unroll
    for (int fn=0; fn<4; fn++){
      float p0 = __expf(s[fn][0]); l0 += p0; Pl[w][g*4+0][fn*16+c] = (__bf16)p0;
      float p1 = __expf(s[fn][1]); l1 += p1; Pl[w][g*4+1][fn*16+c] = (__bf16)p1;
      float p2 = __expf(s[fn][2]); l2 += p2; Pl[w][g*4+2][fn*16+c] = (__bf16)p2;
      float p3 = __expf(s[fn][3]); l3 += p3; Pl[w][g*4+3][fn*16+c] = (__bf16)p3;
    }
    bf16x8 pb0 = *(bf16x8*)&Pl[w][c][     g*8];
    bf16x8 pb1 = *(bf16x8*)&Pl[w][c][32 + g*8];
    #pragma unroll
    for (int fm=0; fm<4; fm++){
      bf16x8 va0 = *(bf16x8*)&Vl[fm*16+c][     g*8];
      bf16x8 va1 = *(bf16x8*)&Vl[fm*16+c][32 + g*8];
      oacc[fm] = __builtin_amdgcn_mfma_f32_16x16x32_bf16(va0, pb0, oacc[fm], 0,0,0);
      oacc[fm] = __builtin_amdgcn_mfma_f32_16x16x32_bf16(va1, pb1, oacc[fm], 0,0,0);
    }
    __syncthreads();
  }

  l0 += __shfl_xor(l0,1); l0 += __shfl_xor(l0,2); l0 += __shfl_xor(l0,4); l0 += __shfl_xor(l0,8);
  l1 += __shfl_xor(l1,1); l1 += __shfl_xor(l1,2); l1 += __shfl_xor(l1,4); l1 += __shfl_xor(l1,8);
  l2 += __shfl_xor(l2,1); l2 += __shfl_xor(l2,2); l2 += __shfl_xor(l2,4); l2 += __shfl_xor(l2,8);
  l3 += __shfl_xor(l3,1); l3 += __shfl_xor(l3,2); l3 += __shfl_xor(l3,4); l3 += __shfl_xor(l3,8);
  float lv = (c==0)?l0:(c==1)?l1:(c==2)?l2:l3;
  if (c < 4) l_lds[w][g*4+c] = lv;
  __syncthreads();
  float linv = 1.0f / l_lds[w][c];

  int qg = qblk*64 + w*16 + c;
  #pragma unroll
  for (int fm=0; fm<4; fm++){
    bf16x4 pk;
    #pragma unroll
    for (int r=0;r<4;r++) pk[r] = (__bf16)(oacc[fm][r]*linv);
    *(bf16x4*)(hout + ((size_t)(bb*NPIX + qg))*CDIM + h*64 + fm*16 + g*4) = pk;
  }
}

extern "C" void kernel_launch(void* const* d_in, const int* in_sizes, int n_in,
                              void* d_out, int out_size, void* d_ws, size_t ws_size,
                              hipStream_t stream) {
  const float* xa  = (const float*)d_in[0];
  const float* xb  = (const float*)d_in[1];
  const float* Wq  = (const float*)d_in[2];
  const float* bq  = (const float*)d_in[3];
  const float* Wk  = (const float*)d_in[4];
  const float* bk  = (const float*)d_in[5];
  const float* Wv  = (const float*)d_in[6];
  const float* bv  = (const float*)d_in[7];
  const float* Wp  = (const float*)d_in[8];
  const float* bp  = (const float*)d_in[9];
  const float* gAw = (const float*)d_in[10];
  const float* gAb = (const float*)d_in[11];
  const float* gBw = (const float*)d_in[12];
  const float* gBb = (const float*)d_in[13];

  char* ws = (char*)d_ws;
  __bf16* wbf   = (__bf16*)(ws + OFF_WBF);
  float2* stats = (float2*)(ws + OFF_STATS);
  __bf16* ant   = (__bf16*)(ws + OFF_ANT);
  __bf16* bnt   = (__bf16*)(ws + OFF_BNT);
  __bf16* qws   = (__bf16*)(ws + OFF_Q);
  __bf16* kws   = (__bf16*)(ws + OFF_K);
  __bf16* vws   = (__bf16*)(ws + OFF_V);
  __bf16* hws   = (__bf16*)(ws + OFF_H);

  prep_w<<<dim3(64,4), 256, 0, stream>>>(Wq, Wk, Wv, Wp, wbf);
  gn_stats<<<1024, 256, 0, stream>>>(xa, xb, stats);
  norm_t<<<dim3(16,64,2), 256, 0, stream>>>(xa, xb, gAw, gAb, gBw, gBb, stats, ant, bnt);
  gemm_qk<<<512, 256, 0, stream>>>(wbf, bnt, ant, bq, bk, qws, kws);
  gemm_sw<<<512, 256, 0, stream>>>(ant, wbf + 2*65536, bv, vws, nullptr, 0);
  attn_k<<<1024, 256, 0, stream>>>(qws, kws, vws, hws);
  gemm_sw<<<512, 256, 0, stream>>>(hws, wbf + 3*65536, bp, d_out, xb, 1);
}

// Round 6
// 174.535 us; speedup vs baseline: 1.4880x; 1.0445x over previous
//
#include <hip/hip_runtime.h>
#include <hip/hip_bf16.h>

#define BSZ 16
#define CDIM 256
#define NPIX 1024
#define NH 4
#define DHD 64
#define EPSV 1e-6f
#define QSCALE 0.0625f   // 1/sqrt(DIM)
#define INV_SQRT2 0.70710678118654752440f

typedef __attribute__((ext_vector_type(4))) float f32x4;
typedef __attribute__((ext_vector_type(8))) __bf16 bf16x8;
typedef __attribute__((ext_vector_type(4))) __bf16 bf16x4;

// async 16B global->LDS (linear dest, per-lane source)
#define ASYNC16(gp, lp) __builtin_amdgcn_global_load_lds( \
    (const __attribute__((address_space(1))) void*)(gp),  \
    (__attribute__((address_space(3))) void*)(lp), 16, 0, 0)

// Workspace layout (bytes). Total = 49.5 MB.
#define OFF_WBF   0UL                          // 4 x 65536 bf16 = 512 KB
#define OFF_STATS (512UL*1024)
#define OFF_ANT   (1024UL*1024)                // [b][p][c] bf16, 8 MB
#define OFF_BNT   (OFF_ANT + 8UL*1024*1024)
#define OFF_Q     (OFF_BNT + 8UL*1024*1024)    // [bh][p][d] bf16
#define OFF_K     (OFF_Q   + 8UL*1024*1024)    // [bh][p][d]
#define OFF_V     (OFF_K   + 8UL*1024*1024)    // [bh][d][p]
#define OFF_H     (OFF_V   + 8UL*1024*1024)    // [b][p][c]

// ---------------- weights -> bf16 (Wq pre-scaled by 1/sqrt(DIM)) -------------
__global__ __launch_bounds__(256) void prep_w(const float* __restrict__ Wq, const float* __restrict__ Wk,
                                              const float* __restrict__ Wv, const float* __restrict__ Wp,
                                              __bf16* __restrict__ out){
  int m = blockIdx.y;
  const float* src = (m==0)?Wq:(m==1)?Wk:(m==2)?Wv:Wp;
  float scale = (m==0)?QSCALE:1.0f;
  int idx = (blockIdx.x*256 + threadIdx.x)*4;
  float4 v = *(const float4*)(src + idx);
  bf16x4 o;
  o[0]=(__bf16)(v.x*scale); o[1]=(__bf16)(v.y*scale);
  o[2]=(__bf16)(v.z*scale); o[3]=(__bf16)(v.w*scale);
  *(bf16x4*)(out + m*65536 + idx) = o;
}

// ---------------- groupnorm stats ------------------------------------------
__global__ __launch_bounds__(256) void gn_stats(const float* __restrict__ xa, const float* __restrict__ xb,
                                                float2* __restrict__ stats){
  int bx = blockIdx.x;              // t(2) * b(16) * g(32)
  int t = bx >> 9; int rem = bx & 511; int bb = rem >> 5; int g = rem & 31;
  const float* src = (t ? xb : xa) + ((size_t)(bb*CDIM + g*8))*NPIX;
  float s = 0.f, ss = 0.f;
  for (int i = 0; i < 8; i++){
    float4 v = *(const float4*)(src + (threadIdx.x + 256*i)*4);
    s  += v.x+v.y+v.z+v.w;
    ss += v.x*v.x+v.y*v.y+v.z*v.z+v.w*v.w;
  }
  __shared__ float rs[256], rss[256];
  rs[threadIdx.x]=s; rss[threadIdx.x]=ss; __syncthreads();
  for (int st=128; st>0; st>>=1){
    if (threadIdx.x < st){ rs[threadIdx.x]+=rs[threadIdx.x+st]; rss[threadIdx.x]+=rss[threadIdx.x+st]; }
    __syncthreads();
  }
  if (threadIdx.x==0){
    float mean = rs[0]*(1.0f/8192.0f);
    float var  = rss[0]*(1.0f/8192.0f) - mean*mean;
    stats[(t*16+bb)*32+g] = make_float2(mean, rsqrtf(var + EPSV));
  }
}

// ------------- normalize + transpose to [b][p][c] bf16 -----------------------
__global__ __launch_bounds__(256) void norm_t(const float* __restrict__ xa, const float* __restrict__ xb,
                                              const float* __restrict__ gAw, const float* __restrict__ gAb,
                                              const float* __restrict__ gBw, const float* __restrict__ gBb,
                                              const float2* __restrict__ stats,
                                              __bf16* __restrict__ ant, __bf16* __restrict__ bnt){
  __shared__ __align__(16) __bf16 T[64][72];
  int t = blockIdx.z;
  const float* src = t ? xb : xa;
  const float* gw  = t ? gBw : gAw;
  const float* gb  = t ? gBb : gAb;
  __bf16* dst = t ? bnt : ant;
  int bb = blockIdx.y >> 2, cblk = blockIdx.y & 3;
  int p0 = blockIdx.x*64, c0 = cblk*64;
  int tid = threadIdx.x;
  int r16 = tid>>4, c4 = tid&15;
  for (int pass=0; pass<4; pass++){
    int cl = r16 + 16*pass;
    int c  = c0 + cl;
    float2 ms = stats[(t*16+bb)*32 + (c>>3)];
    float sc  = ms.y * gw[c];
    float off = gb[c] - ms.x*sc;
    float4 v = *(const float4*)(src + ((size_t)(bb*CDIM + c))*NPIX + p0 + c4*4);
    T[c4*4+0][cl] = (__bf16)(v.x*sc+off);
    T[c4*4+1][cl] = (__bf16)(v.y*sc+off);
    T[c4*4+2][cl] = (__bf16)(v.z*sc+off);
    T[c4*4+3][cl] = (__bf16)(v.w*sc+off);
  }
  __syncthreads();
  for (int pass=0; pass<2; pass++){
    int slot = tid + 256*pass;
    int pl = slot>>3, ch = slot&7;
    *(float4*)(dst + ((size_t)(bb*NPIX + p0 + pl))*CDIM + c0 + ch*8) = *(float4*)&T[pl][ch*8];
  }
}

// ------------- Q+K merged GEMM: 128x128 tile, BK=64, direct staging ----------
__global__ __launch_bounds__(256,2) void gemm_qk(const __bf16* __restrict__ Wqk,
    const __bf16* __restrict__ bnt, const __bf16* __restrict__ ant,
    const float* __restrict__ bq, const float* __restrict__ bk,
    __bf16* __restrict__ qws, __bf16* __restrict__ kws){
  __shared__ __align__(16) __bf16 As[128][76], Bs[128][76];
  int i0 = blockIdx.x;                       // 512 blocks
  int wg = (i0&7)*64 + (i0>>3);              // XCD swizzle (512%8==0, bijective)
  int my = wg&3, nx = wg>>2;                 // blocks sharing B-tile colocate
  int m0 = my*128, n0 = nx*128;
  const __bf16* Bm = (my<2) ? bnt : ant;
  int tid=threadIdx.x, lane=tid&63, wid=tid>>6;
  int wm=(wid>>1)*64, wn=(wid&1)*64, g=lane>>4, c=lane&15;
  f32x4 acc[4][4];
  #pragma unroll
  for (int i=0;i<4;i++)
    #pragma unroll
    for (int j=0;j<4;j++) acc[i][j]=(f32x4){0.f,0.f,0.f,0.f};
  int row[4], ch[4];
  #pragma unroll
  for (int i=0;i<4;i++){ int slot=tid+256*i; row[i]=slot>>3; ch[i]=slot&7; }
  for (int k0=0; k0<256; k0+=64){
    #pragma unroll
    for (int i=0;i<4;i++){
      *(float4*)&As[row[i]][ch[i]*8] = *(const float4*)(Wqk + (size_t)(m0+row[i])*256 + k0 + ch[i]*8);
      *(float4*)&Bs[row[i]][ch[i]*8] = *(const float4*)(Bm  + (size_t)(n0+row[i])*256 + k0 + ch[i]*8);
    }
    __syncthreads();
    #pragma unroll
    for (int ks=0;ks<2;ks++){
      bf16x8 af[4], bfr[4];
      #pragma unroll
      for (int i=0;i<4;i++) af[i]  = *(bf16x8*)&As[wm+i*16+c][ks*32+g*8];
      #pragma unroll
      for (int j=0;j<4;j++) bfr[j] = *(bf16x8*)&Bs[wn+j*16+c][ks*32+g*8];
      #pragma unroll
      for (int i=0;i<4;i++)
        #pragma unroll
        for (int j=0;j<4;j++)
          acc[i][j] = __builtin_amdgcn_mfma_f32_16x16x32_bf16(af[i], bfr[j], acc[i][j],0,0,0);
    }
    __syncthreads();
  }
  const float* bias = (my<2)? bq : bk;
  float bscale = (my<2)? QSCALE : 1.0f;
  __bf16* dst = (my<2)? qws : kws;
  int mbase = (my<2)? m0 : (m0-256);
  #pragma unroll
  for (int fm=0;fm<4;fm++){
    #pragma unroll
    for (int fn=0;fn<4;fn++){
      int o = mbase + wm + fm*16 + g*4;     // out-channel (4 consecutive d)
      int n = n0 + wn + fn*16 + c;
      int bb=n>>10, p=n&1023;
      f32x4 v = acc[fm][fn];
      bf16x4 pk;
      #pragma unroll
      for (int r=0;r<4;r++) pk[r] = (__bf16)(v[r] + bias[o+r]*bscale);
      *(bf16x4*)(dst + ((size_t)((bb*4+(o>>6))*1024 + p))*64 + (o&63)) = pk;
    }
  }
}

// ------------- swapped-orientation GEMM: 128(m=bp) x 64(n=o), direct staging -
__global__ __launch_bounds__(256,2) void gemm_sw(const __bf16* __restrict__ A,
    const __bf16* __restrict__ Wn, const float* __restrict__ bias,
    void* __restrict__ dst_, const float* __restrict__ skip, int mode){
  __shared__ __align__(16) __bf16 As[128][76], Bs[64][76];
  int i0 = blockIdx.x;                       // 512 blocks
  int wg = (i0&7)*64 + (i0>>3);
  int ny = wg&3, mx = wg>>2;                 // blocks sharing A-tile colocate
  int m0 = mx*128, n0 = ny*64;
  int tid=threadIdx.x, lane=tid&63, wid=tid>>6;
  int wm=(wid>>1)*64, wn=(wid&1)*32, g=lane>>4, c=lane&15;
  f32x4 acc[4][2];
  #pragma unroll
  for (int i=0;i<4;i++)
    #pragma unroll
    for (int j=0;j<2;j++) acc[i][j]=(f32x4){0.f,0.f,0.f,0.f};
  int rowA[4], chA[4], rowB[2], chB[2];
  #pragma unroll
  for (int i=0;i<4;i++){ int slot=tid+256*i; rowA[i]=slot>>3; chA[i]=slot&7; }
  #pragma unroll
  for (int i=0;i<2;i++){ int slot=tid+256*i; rowB[i]=slot>>3; chB[i]=slot&7; }
  for (int k0=0; k0<256; k0+=64){
    #pragma unroll
    for (int i=0;i<4;i++)
      *(float4*)&As[rowA[i]][chA[i]*8] = *(const float4*)(A  + (size_t)(m0+rowA[i])*256 + k0 + chA[i]*8);
    #pragma unroll
    for (int i=0;i<2;i++)
      *(float4*)&Bs[rowB[i]][chB[i]*8] = *(const float4*)(Wn + (size_t)(n0+rowB[i])*256 + k0 + chB[i]*8);
    __syncthreads();
    #pragma unroll
    for (int ks=0;ks<2;ks++){
      bf16x8 af[4], bfr[2];
      #pragma unroll
      for (int i=0;i<4;i++) af[i]  = *(bf16x8*)&As[wm+i*16+c][ks*32+g*8];
      #pragma unroll
      for (int j=0;j<2;j++) bfr[j] = *(bf16x8*)&Bs[wn+j*16+c][ks*32+g*8];
      #pragma unroll
      for (int i=0;i<4;i++)
        #pragma unroll
        for (int j=0;j<2;j++)
          acc[i][j] = __builtin_amdgcn_mfma_f32_16x16x32_bf16(af[i], bfr[j], acc[i][j],0,0,0);
    }
    __syncthreads();
  }
  #pragma unroll
  for (int fm=0;fm<4;fm++){
    #pragma unroll
    for (int fn=0;fn<2;fn++){
      int m = m0 + wm + fm*16 + g*4;        // bp (4 consecutive p)
      int n = n0 + wn + fn*16 + c;          // out-channel
      int bb=m>>10, p=m&1023;
      f32x4 v = acc[fm][fn];
      if (mode==0){
        float bv = bias[n];
        bf16x4 pk;
        #pragma unroll
        for (int r=0;r<4;r++) pk[r] = (__bf16)(v[r] + bv);
        *(bf16x4*)((__bf16*)dst_ + ((size_t)((bb*4+(n>>6))*64 + (n&63)))*1024 + p) = pk;
      } else {
        float bv = bias[n];
        size_t addr = (size_t)(bb*256 + n)*1024 + p;
        float4 sk = *(const float4*)(skip + addr);
        float4 ov;
        ov.x=(sk.x+v[0]+bv)*INV_SQRT2; ov.y=(sk.y+v[1]+bv)*INV_SQRT2;
        ov.z=(sk.z+v[2]+bv)*INV_SQRT2; ov.w=(sk.w+v[3]+bv)*INV_SQRT2;
        *(float4*)((float*)dst_ + addr) = ov;
      }
    }
  }
}

// ------------- attention v2: global_load_lds double-buffer, XOR-swizzled LDS -
// K/V staged async into linear LDS with pre-swizzled source (T2 both-sides rule);
// one barrier per K-tile (its built-in vmcnt drain = pipeline sync).
__global__ __launch_bounds__(256,4) void attn_k(const __bf16* __restrict__ q, const __bf16* __restrict__ k,
                                                const __bf16* __restrict__ v, __bf16* __restrict__ hout){
  __shared__ __align__(16) __bf16 Kb[2][4096];   // [64 rows][64 d] per buf, swizzled
  __shared__ __align__(16) __bf16 Vb[2][4096];   // [64 d][64 p] per buf, swizzled
  __shared__ __align__(16) __bf16 Pl[4][1024];   // per-wave [16 q][64 key], swizzled
  int i0 = blockIdx.x;                      // 1024 blocks
  int wg = (i0&7)*128 + (i0>>3);            // XCD swizzle: 8 bh-groups per XCD
  int bh = wg>>4, qblk = wg&15;
  int tid = threadIdx.x, lane = tid&63, w = tid>>6;
  int g = lane>>4, c = lane&15;
  int bb = bh>>2, h = bh&3;
  const char* kbyte = (const char*)(k + (size_t)bh*NPIX*DHD);
  const char* vbyte = (const char*)(v + (size_t)bh*DHD*NPIX);
  const __bf16* qbase = q + (size_t)bh*NPIX*DHD;

  int qrow = qblk*64 + w*16 + c;
  bf16x8 qf0 = *(const bf16x8*)(qbase + (size_t)qrow*64 +      g*8);
  bf16x8 qf1 = *(const bf16x8*)(qbase + (size_t)qrow*64 + 32 + g*8);

  // staging geometry: linear LDS dest (wave-uniform base, HW adds lane*16);
  // source col pre-swizzled: col ^ ((row&7)<<4), row&7 == lane>>3 here.
  int srow = w*8 + (lane>>3);
  int scol = ((lane&7) ^ (lane>>3)) << 4;
  const char* ks0 = kbyte + srow*128 + scol;            // K: [p][d], 128 B rows
  const char* vs0 = vbyte + (size_t)srow*2048 + scol;   // V: [d][p], 2048 B rows

  f32x4 oacc[4];
  #pragma unroll
  for (int i=0;i<4;i++) oacc[i] = (f32x4){0.f,0.f,0.f,0.f};
  float la0=0.f, la1=0.f, la2=0.f, la3=0.f;
  int cs = (c&7)<<4;
  char* pw = (char*)&Pl[w][0];

  #define STAGE(buf, kt) { \
    const char* ks_ = ks0 + (size_t)(kt)*8192; \
    const char* vs_ = vs0 + (size_t)(kt)*128; \
    ASYNC16(ks_,          &Kb[buf][w*512]); \
    ASYNC16(ks_ + 4096,   &Kb[buf][2048 + w*512]); \
    ASYNC16(vs_,          &Vb[buf][w*512]); \
    ASYNC16(vs_ + 65536,  &Vb[buf][2048 + w*512]); }

  STAGE(0, 0)
  for (int kt=0; kt<16; kt++){
    int cur = kt&1;
    __syncthreads();                    // drains vmcnt(0): tile kt landed; buf[cur^1] free
    if (kt<15) STAGE(cur^1, kt+1)
    const char* KL = (const char*)&Kb[cur][0];
    const char* VL = (const char*)&Vb[cur][0];
    // QK^T: S[q=w*16+ (g*4+r)][key = fn*16+c]
    f32x4 s[4];
    #pragma unroll
    for (int fn=0; fn<4; fn++){
      int r = fn*16+c;
      bf16x8 kb0 = *(const bf16x8*)(KL + r*128 + ((     g*16) ^ cs));
      bf16x8 kb1 = *(const bf16x8*)(KL + r*128 + ((64 + g*16) ^ cs));
      f32x4 z = (f32x4){0.f,0.f,0.f,0.f};
      z     = __builtin_amdgcn_mfma_f32_16x16x32_bf16(qf0, kb0, z, 0,0,0);
      s[fn] = __builtin_amdgcn_mfma_f32_16x16x32_bf16(qf1, kb1, z, 0,0,0);
    }
    // P = exp(S), wave-private swizzled store
    #pragma unroll
    for (int fn=0; fn<4; fn++){
      int cb = (fn*16+c)*2;
      float p0 = __expf(s[fn][0]); la0 += p0;
      float p1 = __expf(s[fn][1]); la1 += p1;
      float p2 = __expf(s[fn][2]); la2 += p2;
      float p3 = __expf(s[fn][3]); la3 += p3;
      *(__bf16*)(pw + (g*4+0)*128 + (cb ^ (((g*4+0)&7)<<4))) = (__bf16)p0;
      *(__bf16*)(pw + (g*4+1)*128 + (cb ^ (((g*4+1)&7)<<4))) = (__bf16)p1;
      *(__bf16*)(pw + (g*4+2)*128 + (cb ^ (((g*4+2)&7)<<4))) = (__bf16)p2;
      *(__bf16*)(pw + (g*4+3)*128 + (cb ^ (((g*4+3)&7)<<4))) = (__bf16)p3;
    }
    // h^T += V^T P^T  (DS ops wave-ordered: stores above land before these reads)
    bf16x8 pb0 = *(const bf16x8*)(pw + c*128 + ((     g*16) ^ cs));
    bf16x8 pb1 = *(const bf16x8*)(pw + c*128 + ((64 + g*16) ^ cs));
    #pragma unroll
    for (int fm=0; fm<4; fm++){
      int r = fm*16+c;
      bf16x8 va0 = *(const bf16x8*)(VL + r*128 + ((     g*16) ^ cs));
      bf16x8 va1 = *(const bf16x8*)(VL + r*128 + ((64 + g*16) ^ cs));
      oacc[fm] = __builtin_amdgcn_mfma_f32_16x16x32_bf16(va0, pb0, oacc[fm], 0,0,0);
      oacc[fm] = __builtin_amdgcn_mfma_f32_16x16x32_bf16(va1, pb1, oacc[fm], 0,0,0);
    }
  }
  #undef STAGE

  // softmax denominator: reduce over the 16 c-lanes, broadcast via shfl
  la0 += __shfl_xor(la0,1); la0 += __shfl_xor(la0,2); la0 += __shfl_xor(la0,4); la0 += __shfl_xor(la0,8);
  la1 += __shfl_xor(la1,1); la1 += __shfl_xor(la1,2); la1 += __shfl_xor(la1,4); la1 += __shfl_xor(la1,8);
  la2 += __shfl_xor(la2,1); la2 += __shfl_xor(la2,2); la2 += __shfl_xor(la2,4); la2 += __shfl_xor(la2,8);
  la3 += __shfl_xor(la3,1); la3 += __shfl_xor(la3,2); la3 += __shfl_xor(la3,4); la3 += __shfl_xor(la3,8);
  float vsel = ((c&3)==0)? la0 : ((c&3)==1)? la1 : ((c&3)==2)? la2 : la3;
  float lq = __shfl(vsel, (c>>2)*16 + (c&3));
  float linv = 1.0f / lq;

  int qg = qblk*64 + w*16 + c;
  #pragma unroll
  for (int fm=0; fm<4; fm++){
    bf16x4 pk;
    #pragma unroll
    for (int r=0;r<4;r++) pk[r] = (__bf16)(oacc[fm][r]*linv);
    *(bf16x4*)(hout + ((size_t)(bb*NPIX + qg))*CDIM + h*64 + fm*16 + g*4) = pk;
  }
}

extern "C" void kernel_launch(void* const* d_in, const int* in_sizes, int n_in,
                              void* d_out, int out_size, void* d_ws, size_t ws_size,
                              hipStream_t stream) {
  const float* xa  = (const float*)d_in[0];
  const float* xb  = (const float*)d_in[1];
  const float* Wq  = (const float*)d_in[2];
  const float* bq  = (const float*)d_in[3];
  const float* Wk  = (const float*)d_in[4];
  const float* bk  = (const float*)d_in[5];
  const float* Wv  = (const float*)d_in[6];
  const float* bv  = (const float*)d_in[7];
  const float* Wp  = (const float*)d_in[8];
  const float* bp  = (const float*)d_in[9];
  const float* gAw = (const float*)d_in[10];
  const float* gAb = (const float*)d_in[11];
  const float* gBw = (const float*)d_in[12];
  const float* gBb = (const float*)d_in[13];

  char* ws = (char*)d_ws;
  __bf16* wbf   = (__bf16*)(ws + OFF_WBF);
  float2* stats = (float2*)(ws + OFF_STATS);
  __bf16* ant   = (__bf16*)(ws + OFF_ANT);
  __bf16* bnt   = (__bf16*)(ws + OFF_BNT);
  __bf16* qws   = (__bf16*)(ws + OFF_Q);
  __bf16* kws   = (__bf16*)(ws + OFF_K);
  __bf16* vws   = (__bf16*)(ws + OFF_V);
  __bf16* hws   = (__bf16*)(ws + OFF_H);

  prep_w<<<dim3(64,4), 256, 0, stream>>>(Wq, Wk, Wv, Wp, wbf);
  gn_stats<<<1024, 256, 0, stream>>>(xa, xb, stats);
  norm_t<<<dim3(16,64,2), 256, 0, stream>>>(xa, xb, gAw, gAb, gBw, gBb, stats, ant, bnt);
  gemm_qk<<<512, 256, 0, stream>>>(wbf, bnt, ant, bq, bk, qws, kws);
  gemm_sw<<<512, 256, 0, stream>>>(ant, wbf + 2*65536, bv, vws, nullptr, 0);
  attn_k<<<1024, 256, 0, stream>>>(qws, kws, vws, hws);
  gemm_sw<<<512, 256, 0, stream>>>(hws, wbf + 3*65536, bp, d_out, xb, 1);
}

// Round 10
// 171.789 us; speedup vs baseline: 1.5118x; 1.0160x over previous
//
#include <hip/hip_runtime.h>
#include <hip/hip_bf16.h>

#define BSZ 16
#define CDIM 256
#define NPIX 1024
#define NH 4
#define DHD 64
#define EPSV 1e-6f
#define QSCALE 0.0625f   // 1/sqrt(DIM)
#define INV_SQRT2 0.70710678118654752440f

typedef __attribute__((ext_vector_type(4))) float f32x4;
typedef __attribute__((ext_vector_type(8))) __bf16 bf16x8;
typedef __attribute__((ext_vector_type(4))) __bf16 bf16x4;

// async 16B global->LDS (linear dest, per-lane source)
#define ASYNC16(gp, lp) __builtin_amdgcn_global_load_lds( \
    (const __attribute__((address_space(1))) void*)(gp),  \
    (__attribute__((address_space(3))) void*)(lp), 16, 0, 0)

// Workspace layout (bytes). Total = 49.5 MB.
#define OFF_WBF   0UL                          // 4 x 65536 bf16 = 512 KB
#define OFF_STATS (512UL*1024)
#define OFF_ANT   (1024UL*1024)                // [b][p][c] bf16, 8 MB
#define OFF_BNT   (OFF_ANT + 8UL*1024*1024)
#define OFF_Q     (OFF_BNT + 8UL*1024*1024)    // [bh][p][d] bf16
#define OFF_K     (OFF_Q   + 8UL*1024*1024)    // [bh][p][d]
#define OFF_V     (OFF_K   + 8UL*1024*1024)    // [bh][d][p]
#define OFF_H     (OFF_V   + 8UL*1024*1024)    // [b][p][c]

// ---------------- weights -> bf16 (Wq pre-scaled by 1/sqrt(DIM)) -------------
__global__ __launch_bounds__(256) void prep_w(const float* __restrict__ Wq, const float* __restrict__ Wk,
                                              const float* __restrict__ Wv, const float* __restrict__ Wp,
                                              __bf16* __restrict__ out){
  int m = blockIdx.y;
  const float* src = (m==0)?Wq:(m==1)?Wk:(m==2)?Wv:Wp;
  float scale = (m==0)?QSCALE:1.0f;
  int idx = (blockIdx.x*256 + threadIdx.x)*4;
  float4 v = *(const float4*)(src + idx);
  bf16x4 o;
  o[0]=(__bf16)(v.x*scale); o[1]=(__bf16)(v.y*scale);
  o[2]=(__bf16)(v.z*scale); o[3]=(__bf16)(v.w*scale);
  *(bf16x4*)(out + m*65536 + idx) = o;
}

// ------------- fused groupnorm: stats + normalize + transpose, one HBM pass --
// block = one (tensor, batch, group) slice: 8 ch x 1024 px = 32 KB fp32 in LDS
__global__ __launch_bounds__(256) void gn_fused(const float* __restrict__ xa, const float* __restrict__ xb,
    const float* __restrict__ gAw, const float* __restrict__ gAb,
    const float* __restrict__ gBw, const float* __restrict__ gBb,
    __bf16* __restrict__ ant, __bf16* __restrict__ bnt){
  __shared__ float S[8192];       // [ch][px] fp32 slice, 32 KB
  __shared__ float red[8];
  int bx = blockIdx.x;            // t(2) * b(16) * g(32)
  int t = bx>>9, rem = bx&511, b = rem>>5, g = rem&31;
  const float* src = (t ? xb : xa) + ((size_t)(b*CDIM + g*8))*NPIX;
  const float* gw  = t ? gBw : gAw;
  const float* gb  = t ? gBb : gAb;
  __bf16* dst = (t ? bnt : ant) + (size_t)b*NPIX*CDIM + g*8;
  int tid = threadIdx.x, lane = tid&63, w = tid>>6;
  float s=0.f, ss=0.f;
  #pragma unroll
  for (int k=0;k<8;k++){
    int flat = tid + 256*k;        // float4 index: ch = flat>>8, px4 = flat&255
    float4 v = *(const float4*)(src + (size_t)flat*4);
    *(float4*)&S[flat*4] = v;
    s  += v.x+v.y+v.z+v.w;
    ss += v.x*v.x+v.y*v.y+v.z*v.z+v.w*v.w;
  }
  #pragma unroll
  for (int m=32;m>0;m>>=1){ s += __shfl_xor(s,m); ss += __shfl_xor(ss,m); }
  if (lane==0){ red[w]=s; red[4+w]=ss; }
  __syncthreads();
  float st  = red[0]+red[1]+red[2]+red[3];
  float sst = red[4]+red[5]+red[6]+red[7];
  float mean = st*(1.0f/8192.0f);
  float var  = sst*(1.0f/8192.0f) - mean*mean;
  float rstd = rsqrtf(var + EPSV);
  float sc[8], off[8];
  #pragma unroll
  for (int c2=0;c2<8;c2++){ sc[c2]=rstd*gw[g*8+c2]; off[c2]=gb[g*8+c2]-mean*sc[c2]; }
  #pragma unroll
  for (int k=0;k<4;k++){
    int px = tid + 256*k;
    bf16x8 o;
    #pragma unroll
    for (int c2=0;c2<8;c2++) o[c2] = (__bf16)(S[c2*1024+px]*sc[c2]+off[c2]);
    *(bf16x8*)(dst + (size_t)px*CDIM) = o;   // 16B at [b][px][g*8]
  }
}

// ------------- merged Q/K/V projections: blocks 0-511 QK, 512-1023 V ---------
// QK: A = stacked [Wq*s; Wk] (512x256), 128x128 tile -> [bh][p][d]
// V : A = ant (m=bp), B = Wv, 128x64 tile -> [bh][d][p]
__global__ __launch_bounds__(256,2) void gemm_qkv(const __bf16* __restrict__ Wqk,
    const __bf16* __restrict__ bnt, const __bf16* __restrict__ ant,
    const float* __restrict__ bq, const float* __restrict__ bk,
    __bf16* __restrict__ qws, __bf16* __restrict__ kws,
    const __bf16* __restrict__ Wv, const float* __restrict__ bv,
    __bf16* __restrict__ vws){
  __shared__ __align__(16) __bf16 As[128][76], Bs[128][76];
  int tid=threadIdx.x, lane=tid&63, wid=tid>>6;
  int g=lane>>4, c=lane&15;
  if (blockIdx.x < 512){
    int i0 = blockIdx.x;
    int wg = (i0&7)*64 + (i0>>3);            // XCD swizzle (bijective, 512%8==0)
    int my = wg&3, nx = wg>>2;
    int m0 = my*128, n0 = nx*128;
    const __bf16* Bm = (my<2) ? bnt : ant;
    int wm=(wid>>1)*64, wn=(wid&1)*64;
    f32x4 acc[4][4];
    #pragma unroll
    for (int i=0;i<4;i++)
      #pragma unroll
      for (int j=0;j<4;j++) acc[i][j]=(f32x4){0.f,0.f,0.f,0.f};
    int row[4], ch[4];
    #pragma unroll
    for (int i=0;i<4;i++){ int slot=tid+256*i; row[i]=slot>>3; ch[i]=slot&7; }
    for (int k0=0; k0<256; k0+=64){
      #pragma unroll
      for (int i=0;i<4;i++){
        *(float4*)&As[row[i]][ch[i]*8] = *(const float4*)(Wqk + (size_t)(m0+row[i])*256 + k0 + ch[i]*8);
        *(float4*)&Bs[row[i]][ch[i]*8] = *(const float4*)(Bm  + (size_t)(n0+row[i])*256 + k0 + ch[i]*8);
      }
      __syncthreads();
      #pragma unroll
      for (int ks=0;ks<2;ks++){
        bf16x8 af[4], bfr[4];
        #pragma unroll
        for (int i=0;i<4;i++) af[i]  = *(bf16x8*)&As[wm+i*16+c][ks*32+g*8];
        #pragma unroll
        for (int j=0;j<4;j++) bfr[j] = *(bf16x8*)&Bs[wn+j*16+c][ks*32+g*8];
        #pragma unroll
        for (int i=0;i<4;i++)
          #pragma unroll
          for (int j=0;j<4;j++)
            acc[i][j] = __builtin_amdgcn_mfma_f32_16x16x32_bf16(af[i], bfr[j], acc[i][j],0,0,0);
      }
      __syncthreads();
    }
    const float* bias = (my<2)? bq : bk;
    float bscale = (my<2)? QSCALE : 1.0f;
    __bf16* dst = (my<2)? qws : kws;
    int mbase = (my<2)? m0 : (m0-256);
    #pragma unroll
    for (int fm=0;fm<4;fm++){
      #pragma unroll
      for (int fn=0;fn<4;fn++){
        int o = mbase + wm + fm*16 + g*4;
        int n = n0 + wn + fn*16 + c;
        int bb=n>>10, p=n&1023;
        f32x4 v = acc[fm][fn];
        bf16x4 pk;
        #pragma unroll
        for (int r=0;r<4;r++) pk[r] = (__bf16)(v[r] + bias[o+r]*bscale);
        *(bf16x4*)(dst + ((size_t)((bb*4+(o>>6))*1024 + p))*64 + (o&63)) = pk;
      }
    }
  } else {
    int i0 = blockIdx.x - 512;
    int wg = (i0&7)*64 + (i0>>3);
    int ny = wg&3, mx = wg>>2;
    int m0 = mx*128, n0 = ny*64;
    int wm=(wid>>1)*64, wn=(wid&1)*32;
    f32x4 acc[4][2];
    #pragma unroll
    for (int i=0;i<4;i++)
      #pragma unroll
      for (int j=0;j<2;j++) acc[i][j]=(f32x4){0.f,0.f,0.f,0.f};
    int rowA[4], chA[4], rowB[2], chB[2];
    #pragma unroll
    for (int i=0;i<4;i++){ int slot=tid+256*i; rowA[i]=slot>>3; chA[i]=slot&7; }
    #pragma unroll
    for (int i=0;i<2;i++){ int slot=tid+256*i; rowB[i]=slot>>3; chB[i]=slot&7; }
    for (int k0=0; k0<256; k0+=64){
      #pragma unroll
      for (int i=0;i<4;i++)
        *(float4*)&As[rowA[i]][chA[i]*8] = *(const float4*)(ant + (size_t)(m0+rowA[i])*256 + k0 + chA[i]*8);
      #pragma unroll
      for (int i=0;i<2;i++)
        *(float4*)&Bs[rowB[i]][chB[i]*8] = *(const float4*)(Wv  + (size_t)(n0+rowB[i])*256 + k0 + chB[i]*8);
      __syncthreads();
      #pragma unroll
      for (int ks=0;ks<2;ks++){
        bf16x8 af[4], bfr[2];
        #pragma unroll
        for (int i=0;i<4;i++) af[i]  = *(bf16x8*)&As[wm+i*16+c][ks*32+g*8];
        #pragma unroll
        for (int j=0;j<2;j++) bfr[j] = *(bf16x8*)&Bs[wn+j*16+c][ks*32+g*8];
        #pragma unroll
        for (int i=0;i<4;i++)
          #pragma unroll
          for (int j=0;j<2;j++)
            acc[i][j] = __builtin_amdgcn_mfma_f32_16x16x32_bf16(af[i], bfr[j], acc[i][j],0,0,0);
      }
      __syncthreads();
    }
    #pragma unroll
    for (int fm=0;fm<4;fm++){
      #pragma unroll
      for (int fn=0;fn<2;fn++){
        int m = m0 + wm + fm*16 + g*4;      // bp (4 consecutive p)
        int n = n0 + wn + fn*16 + c;        // out-channel
        int bb=m>>10, p=m&1023;
        f32x4 v = acc[fm][fn];
        float bvv = bv[n];
        bf16x4 pk;
        #pragma unroll
        for (int r=0;r<4;r++) pk[r] = (__bf16)(v[r] + bvv);
        *(bf16x4*)(vws + ((size_t)((bb*4+(n>>6))*64 + (n&63)))*1024 + p) = pk;
      }
    }
  }
}

// ------------- out-projection GEMM: 128(m=bp) x 64(n=o), K=256 ---------------
__global__ __launch_bounds__(256,2) void gemm_sw(const __bf16* __restrict__ A,
    const __bf16* __restrict__ Wn, const float* __restrict__ bias,
    void* __restrict__ dst_, const float* __restrict__ skip, int mode){
  __shared__ __align__(16) __bf16 As[128][76], Bs[64][76];
  int i0 = blockIdx.x;                       // 512 blocks
  int wg = (i0&7)*64 + (i0>>3);
  int ny = wg&3, mx = wg>>2;                 // blocks sharing A-tile colocate
  int m0 = mx*128, n0 = ny*64;
  int tid=threadIdx.x, lane=tid&63, wid=tid>>6;
  int wm=(wid>>1)*64, wn=(wid&1)*32, g=lane>>4, c=lane&15;
  f32x4 acc[4][2];
  #pragma unroll
  for (int i=0;i<4;i++)
    #pragma unroll
    for (int j=0;j<2;j++) acc[i][j]=(f32x4){0.f,0.f,0.f,0.f};
  int rowA[4], chA[4], rowB[2], chB[2];
  #pragma unroll
  for (int i=0;i<4;i++){ int slot=tid+256*i; rowA[i]=slot>>3; chA[i]=slot&7; }
  #pragma unroll
  for (int i=0;i<2;i++){ int slot=tid+256*i; rowB[i]=slot>>3; chB[i]=slot&7; }
  for (int k0=0; k0<256; k0+=64){
    #pragma unroll
    for (int i=0;i<4;i++)
      *(float4*)&As[rowA[i]][chA[i]*8] = *(const float4*)(A  + (size_t)(m0+rowA[i])*256 + k0 + chA[i]*8);
    #pragma unroll
    for (int i=0;i<2;i++)
      *(float4*)&Bs[rowB[i]][chB[i]*8] = *(const float4*)(Wn + (size_t)(n0+rowB[i])*256 + k0 + chB[i]*8);
    __syncthreads();
    #pragma unroll
    for (int ks=0;ks<2;ks++){
      bf16x8 af[4], bfr[2];
      #pragma unroll
      for (int i=0;i<4;i++) af[i]  = *(bf16x8*)&As[wm+i*16+c][ks*32+g*8];
      #pragma unroll
      for (int j=0;j<2;j++) bfr[j] = *(bf16x8*)&Bs[wn+j*16+c][ks*32+g*8];
      #pragma unroll
      for (int i=0;i<4;i++)
        #pragma unroll
        for (int j=0;j<2;j++)
          acc[i][j] = __builtin_amdgcn_mfma_f32_16x16x32_bf16(af[i], bfr[j], acc[i][j],0,0,0);
    }
    __syncthreads();
  }
  #pragma unroll
  for (int fm=0;fm<4;fm++){
    #pragma unroll
    for (int fn=0;fn<2;fn++){
      int m = m0 + wm + fm*16 + g*4;        // bp (4 consecutive p)
      int n = n0 + wn + fn*16 + c;          // out-channel
      int bb=m>>10, p=m&1023;
      f32x4 v = acc[fm][fn];
      if (mode==0){
        float bvv = bias[n];
        bf16x4 pk;
        #pragma unroll
        for (int r=0;r<4;r++) pk[r] = (__bf16)(v[r] + bvv);
        *(bf16x4*)((__bf16*)dst_ + ((size_t)((bb*4+(n>>6))*64 + (n&63)))*1024 + p) = pk;
      } else {
        float bvv = bias[n];
        size_t addr = (size_t)(bb*256 + n)*1024 + p;
        float4 sk = *(const float4*)(skip + addr);
        float4 ov;
        ov.x=(sk.x+v[0]+bvv)*INV_SQRT2; ov.y=(sk.y+v[1]+bvv)*INV_SQRT2;
        ov.z=(sk.z+v[2]+bvv)*INV_SQRT2; ov.w=(sk.w+v[3]+bvv)*INV_SQRT2;
        *(float4*)((float*)dst_ + addr) = ov;
      }
    }
  }
}

// ------------- attention v2: global_load_lds double-buffer, XOR-swizzled LDS -
__global__ __launch_bounds__(256,4) void attn_k(const __bf16* __restrict__ q, const __bf16* __restrict__ k,
                                                const __bf16* __restrict__ v, __bf16* __restrict__ hout){
  __shared__ __align__(16) __bf16 Kb[2][4096];   // [64 rows][64 d] per buf, swizzled
  __shared__ __align__(16) __bf16 Vb[2][4096];   // [64 d][64 p] per buf, swizzled
  __shared__ __align__(16) __bf16 Pl[4][1024];   // per-wave [16 q][64 key], swizzled
  int i0 = blockIdx.x;                      // 1024 blocks
  int wg = (i0&7)*128 + (i0>>3);            // XCD swizzle: 8 bh-groups per XCD
  int bh = wg>>4, qblk = wg&15;
  int tid = threadIdx.x, lane = tid&63, w = tid>>6;
  int g = lane>>4, c = lane&15;
  int bb = bh>>2, h = bh&3;
  const char* kbyte = (const char*)(k + (size_t)bh*NPIX*DHD);
  const char* vbyte = (const char*)(v + (size_t)bh*DHD*NPIX);
  const __bf16* qbase = q + (size_t)bh*NPIX*DHD;

  int qrow = qblk*64 + w*16 + c;
  bf16x8 qf0 = *(const bf16x8*)(qbase + (size_t)qrow*64 +      g*8);
  bf16x8 qf1 = *(const bf16x8*)(qbase + (size_t)qrow*64 + 32 + g*8);

  int srow = w*8 + (lane>>3);
  int scol = ((lane&7) ^ (lane>>3)) << 4;
  const char* ks0 = kbyte + srow*128 + scol;            // K: [p][d], 128 B rows
  const char* vs0 = vbyte + (size_t)srow*2048 + scol;   // V: [d][p], 2048 B rows

  f32x4 oacc[4];
  #pragma unroll
  for (int i=0;i<4;i++) oacc[i] = (f32x4){0.f,0.f,0.f,0.f};
  float la0=0.f, la1=0.f, la2=0.f, la3=0.f;
  int cs = (c&7)<<4;
  char* pw = (char*)&Pl[w][0];

  #define STAGE(buf, kt) { \
    const char* ks_ = ks0 + (size_t)(kt)*8192; \
    const char* vs_ = vs0 + (size_t)(kt)*128; \
    ASYNC16(ks_,          &Kb[buf][w*512]); \
    ASYNC16(ks_ + 4096,   &Kb[buf][2048 + w*512]); \
    ASYNC16(vs_,          &Vb[buf][w*512]); \
    ASYNC16(vs_ + 65536,  &Vb[buf][2048 + w*512]); }

  STAGE(0, 0)
  for (int kt=0; kt<16; kt++){
    int cur = kt&1;
    __syncthreads();                    // drains vmcnt(0): tile kt landed
    if (kt<15) STAGE(cur^1, kt+1)
    const char* KL = (const char*)&Kb[cur][0];
    const char* VL = (const char*)&Vb[cur][0];
    f32x4 s[4];
    #pragma unroll
    for (int fn=0; fn<4; fn++){
      int r = fn*16+c;
      bf16x8 kb0 = *(const bf16x8*)(KL + r*128 + ((     g*16) ^ cs));
      bf16x8 kb1 = *(const bf16x8*)(KL + r*128 + ((64 + g*16) ^ cs));
      f32x4 z = (f32x4){0.f,0.f,0.f,0.f};
      z     = __builtin_amdgcn_mfma_f32_16x16x32_bf16(qf0, kb0, z, 0,0,0);
      s[fn] = __builtin_amdgcn_mfma_f32_16x16x32_bf16(qf1, kb1, z, 0,0,0);
    }
    #pragma unroll
    for (int fn=0; fn<4; fn++){
      int cb = (fn*16+c)*2;
      float p0 = __expf(s[fn][0]); la0 += p0;
      float p1 = __expf(s[fn][1]); la1 += p1;
      float p2 = __expf(s[fn][2]); la2 += p2;
      float p3 = __expf(s[fn][3]); la3 += p3;
      *(__bf16*)(pw + (g*4+0)*128 + (cb ^ (((g*4+0)&7)<<4))) = (__bf16)p0;
      *(__bf16*)(pw + (g*4+1)*128 + (cb ^ (((g*4+1)&7)<<4))) = (__bf16)p1;
      *(__bf16*)(pw + (g*4+2)*128 + (cb ^ (((g*4+2)&7)<<4))) = (__bf16)p2;
      *(__bf16*)(pw + (g*4+3)*128 + (cb ^ (((g*4+3)&7)<<4))) = (__bf16)p3;
    }
    bf16x8 pb0 = *(const bf16x8*)(pw + c*128 + ((     g*16) ^ cs));
    bf16x8 pb1 = *(const bf16x8*)(pw + c*128 + ((64 + g*16) ^ cs));
    #pragma unroll
    for (int fm=0; fm<4; fm++){
      int r = fm*16+c;
      bf16x8 va0 = *(const bf16x8*)(VL + r*128 + ((     g*16) ^ cs));
      bf16x8 va1 = *(const bf16x8*)(VL + r*128 + ((64 + g*16) ^ cs));
      oacc[fm] = __builtin_amdgcn_mfma_f32_16x16x32_bf16(va0, pb0, oacc[fm], 0,0,0);
      oacc[fm] = __builtin_amdgcn_mfma_f32_16x16x32_bf16(va1, pb1, oacc[fm], 0,0,0);
    }
  }
  #undef STAGE

  la0 += __shfl_xor(la0,1); la0 += __shfl_xor(la0,2); la0 += __shfl_xor(la0,4); la0 += __shfl_xor(la0,8);
  la1 += __shfl_xor(la1,1); la1 += __shfl_xor(la1,2); la1 += __shfl_xor(la1,4); la1 += __shfl_xor(la1,8);
  la2 += __shfl_xor(la2,1); la2 += __shfl_xor(la2,2); la2 += __shfl_xor(la2,4); la2 += __shfl_xor(la2,8);
  la3 += __shfl_xor(la3,1); la3 += __shfl_xor(la3,2); la3 += __shfl_xor(la3,4); la3 += __shfl_xor(la3,8);
  float vsel = ((c&3)==0)? la0 : ((c&3)==1)? la1 : ((c&3)==2)? la2 : la3;
  float lq = __shfl(vsel, (c>>2)*16 + (c&3));
  float linv = 1.0f / lq;

  int qg = qblk*64 + w*16 + c;
  #pragma unroll
  for (int fm=0; fm<4; fm++){
    bf16x4 pk;
    #pragma unroll
    for (int r=0;r<4;r++) pk[r] = (__bf16)(oacc[fm][r]*linv);
    *(bf16x4*)(hout + ((size_t)(bb*NPIX + qg))*CDIM + h*64 + fm*16 + g*4) = pk;
  }
}

extern "C" void kernel_launch(void* const* d_in, const int* in_sizes, int n_in,
                              void* d_out, int out_size, void* d_ws, size_t ws_size,
                              hipStream_t stream) {
  const float* xa  = (const float*)d_in[0];
  const float* xb  = (const float*)d_in[1];
  const float* Wq  = (const float*)d_in[2];
  const float* bq  = (const float*)d_in[3];
  const float* Wk  = (const float*)d_in[4];
  const float* bk  = (const float*)d_in[5];
  const float* Wv  = (const float*)d_in[6];
  const float* bv  = (const float*)d_in[7];
  const float* Wp  = (const float*)d_in[8];
  const float* bp  = (const float*)d_in[9];
  const float* gAw = (const float*)d_in[10];
  const float* gAb = (const float*)d_in[11];
  const float* gBw = (const float*)d_in[12];
  const float* gBb = (const float*)d_in[13];

  char* ws = (char*)d_ws;
  __bf16* wbf   = (__bf16*)(ws + OFF_WBF);
  __bf16* ant   = (__bf16*)(ws + OFF_ANT);
  __bf16* bnt   = (__bf16*)(ws + OFF_BNT);
  __bf16* qws   = (__bf16*)(ws + OFF_Q);
  __bf16* kws   = (__bf16*)(ws + OFF_K);
  __bf16* vws   = (__bf16*)(ws + OFF_V);
  __bf16* hws   = (__bf16*)(ws + OFF_H);

  prep_w<<<dim3(64,4), 256, 0, stream>>>(Wq, Wk, Wv, Wp, wbf);
  gn_fused<<<1024, 256, 0, stream>>>(xa, xb, gAw, gAb, gBw, gBb, ant, bnt);
  gemm_qkv<<<1024, 256, 0, stream>>>(wbf, bnt, ant, bq, bk, qws, kws,
                                     wbf + 2*65536, bv, vws);
  attn_k<<<1024, 256, 0, stream>>>(qws, kws, vws, hws);
  gemm_sw<<<512, 256, 0, stream>>>(hws, wbf + 3*65536, bp, d_out, xb, 1);
}